// Round 15
// baseline (462.216 us; speedup 1.0000x reference)
//
#include <hip/hip_runtime.h>

#define N_NODES 100000
#define N_EDGES 400000
#define N_GRAPHS 2000
#define F_IN 74
#define ENC_KP 96
#define HID 64
#define NHEAD 4
#define HID4 256
#define OUT_DIM 128
#define NODES_PER_G 50

typedef __attribute__((ext_vector_type(8))) short short8;
typedef __attribute__((ext_vector_type(4))) float f32x4;

__device__ inline ushort f2bf(float f) {
  union { float f; unsigned u; } v; v.f = f;
  unsigned u = v.u;
  return (ushort)((u + 0x7FFFu + ((u >> 16) & 1u)) >> 16);
}
__device__ inline float bf2f(ushort b) {
  union { unsigned u; float f; } v; v.u = ((unsigned)b) << 16;
  return v.f;
}
__device__ inline float leaky(float x) { return x >= 0.f ? x : 0.2f * x; }

// async global->LDS, 16B per lane, dest = uniform base + lane*16
__device__ inline void glds16(const ushort* g, ushort* l) {
  __builtin_amdgcn_global_load_lds(
      (const __attribute__((address_space(1))) void*)g,
      (__attribute__((address_space(3))) void*)l, 16, 0, 0);
}

// ---------------------------------------------------------------- CSR build
__global__ __launch_bounds__(256) void k_count(const int* __restrict__ dst,
                                               int* __restrict__ off) {
  int e = blockIdx.x * 256 + threadIdx.x;
  if (e < N_EDGES) atomicAdd(&off[dst[e] + 1], 1);
}

__global__ __launch_bounds__(256) void k_scan1(int* __restrict__ data, int n,
                                               int* __restrict__ blksum) {
  __shared__ int sh[256];
  int t = threadIdx.x;
  int base = blockIdx.x * 1024 + t * 4;
  int v0 = (base + 0 < n) ? data[base + 0] : 0;
  int v1 = (base + 1 < n) ? data[base + 1] : 0;
  int v2 = (base + 2 < n) ? data[base + 2] : 0;
  int v3 = (base + 3 < n) ? data[base + 3] : 0;
  v1 += v0; v2 += v1; v3 += v2;
  int tot = v3;
  sh[t] = tot;
  __syncthreads();
  for (int o = 1; o < 256; o <<= 1) {
    int x = (t >= o) ? sh[t - o] : 0;
    __syncthreads();
    sh[t] += x;
    __syncthreads();
  }
  int excl = sh[t] - tot;
  if (base + 0 < n) data[base + 0] = v0 + excl;
  if (base + 1 < n) data[base + 1] = v1 + excl;
  if (base + 2 < n) data[base + 2] = v2 + excl;
  if (base + 3 < n) data[base + 3] = v3 + excl;
  if (t == 255) blksum[blockIdx.x] = sh[255];
}

__global__ __launch_bounds__(256) void k_scan2(int* __restrict__ blksum, int nb) {
  __shared__ int sh[256];
  int t = threadIdx.x;
  sh[t] = (t < nb) ? blksum[t] : 0;
  __syncthreads();
  for (int o = 1; o < 256; o <<= 1) {
    int x = (t >= o) ? sh[t - o] : 0;
    __syncthreads();
    sh[t] += x;
    __syncthreads();
  }
  if (t < nb) blksum[t] = sh[t];
}

__global__ __launch_bounds__(256) void k_scan3(int* __restrict__ data, int n,
                                               const int* __restrict__ blksum) {
  int b = blockIdx.x;
  if (b == 0) return;
  int add = blksum[b - 1];
  int base = b * 1024 + threadIdx.x * 4;
  for (int j = 0; j < 4; ++j)
    if (base + j < n) data[base + j] += add;
}

__global__ __launch_bounds__(256) void k_scatter(const int* __restrict__ dst,
                                                 const int* __restrict__ src,
                                                 const int* __restrict__ off,
                                                 int* __restrict__ cursor,
                                                 int* __restrict__ srcs) {
  int e = blockIdx.x * 256 + threadIdx.x;
  if (e >= N_EDGES) return;
  int d = dst[e];
  int pos = off[d] + atomicAdd(&cursor[d], 1);
  srcs[pos] = src[e];
}

__global__ __launch_bounds__(256) void k_sortseg(const int* __restrict__ off,
                                                 int* __restrict__ srcs) {
  int n = blockIdx.x * 256 + threadIdx.x;
  if (n >= N_NODES) return;
  int beg = off[n], end = off[n + 1];
  for (int i = beg + 1; i < end; ++i) {
    int key = srcs[i];
    int j = i - 1;
    while (j >= beg && srcs[j] > key) { srcs[j + 1] = srcs[j]; --j; }
    srcs[j + 1] = key;
  }
}

// ------------------------- consolidated weight prep (one launch, upfront)
// Fused encoder+layer0: Wcomb[256][96] = (We@W0)^T, bcomb[256] = be@W0,
// Wlrc[16][96] = (We_pad @ (W0@al|ar))^T, elc[8] = be@(W0@al|ar).
// Layers 1,2: Wt_l [256][256]; Wlr_l [16][256].
__global__ __launch_bounds__(256) void k_prep(
    const float* __restrict__ enc_W, const float* __restrict__ enc_b,
    const float* __restrict__ W0, const float* __restrict__ W1,
    const float* __restrict__ W2,
    const float* __restrict__ al0, const float* __restrict__ ar0,
    const float* __restrict__ al1, const float* __restrict__ ar1,
    const float* __restrict__ al2, const float* __restrict__ ar2,
    ushort* __restrict__ Wcomb, float* __restrict__ bcomb,
    ushort* __restrict__ Wlrc, float* __restrict__ elc,
    ushort* __restrict__ Wt1, ushort* __restrict__ Wt2,
    ushort* __restrict__ Wlr1, ushort* __restrict__ Wlr2) {
  const int S0 = HID4 * ENC_KP;          // Wcomb
  const int S1 = S0 + HID4;              // bcomb
  const int S2 = S1 + 16 * ENC_KP;       // Wlrc
  const int S3 = S2 + 8;                 // elc
  const int S4 = S3 + HID4 * HID4;       // Wt1
  const int S5 = S4 + HID4 * HID4;       // Wt2
  const int S6 = S5 + 16 * HID4;         // Wlr1
  const int S7 = S6 + 16 * HID4;         // Wlr2
  int idx = blockIdx.x * 256 + threadIdx.x;
  if (idx < S0) {
    int c = idx / ENC_KP, k = idx - c * ENC_KP;
    float acc = 0.f;
    if (k < F_IN) {
      const float* we = enc_W + (size_t)k * HID;
      for (int o = 0; o < HID; ++o) acc = fmaf(we[o], W0[(size_t)o * HID4 + c], acc);
    }
    Wcomb[idx] = f2bf(acc);
  } else if (idx < S1) {
    int c = idx - S0;
    float acc = 0.f;
    for (int o = 0; o < HID; ++o) acc = fmaf(enc_b[o], W0[(size_t)o * HID4 + c], acc);
    bcomb[c] = acc;
  } else if (idx < S2) {
    int i = idx - S1;
    int c = i / ENC_KP, k = i - c * ENC_KP;
    float acc = 0.f;
    if (c < 8 && k < F_IN) {
      const float* av = (c < 4) ? al0 + (c & 3) * 64 : ar0 + (c & 3) * 64;
      const float* we = enc_W + (size_t)k * HID;
      for (int o = 0; o < HID; ++o) {
        float w = 0.f;
        const float* wp = W0 + (size_t)o * HID4 + (c & 3) * 64;
        for (int j = 0; j < 64; ++j) w = fmaf(wp[j], av[j], w);
        acc = fmaf(we[o], w, acc);
      }
    }
    Wlrc[i] = f2bf(acc);
  } else if (idx < S3) {
    int c = idx - S2;
    float acc = 0.f;
    const float* av = (c < 4) ? al0 + (c & 3) * 64 : ar0 + (c & 3) * 64;
    for (int o = 0; o < HID; ++o) {
      float w = 0.f;
      const float* wp = W0 + (size_t)o * HID4 + (c & 3) * 64;
      for (int j = 0; j < 64; ++j) w = fmaf(wp[j], av[j], w);
      acc = fmaf(enc_b[o], w, acc);
    }
    elc[c] = acc;
  } else if (idx < S4) {
    int i = idx - S3; int k = i >> 8, n = i & 255;
    Wt1[(size_t)n * HID4 + k] = f2bf(W1[i]);
  } else if (idx < S5) {
    int i = idx - S4; int k = i >> 8, n = i & 255;
    Wt2[(size_t)n * HID4 + k] = f2bf(W2[i]);
  } else if (idx < S6) {
    int i = idx - S5; int c = i / HID4, k = i - c * HID4;
    float acc = 0.f;
    if (c < 8) {
      const float* av = (c < 4) ? al1 + (c & 3) * 64 : ar1 + (c & 3) * 64;
      const float* wp = W1 + (size_t)k * HID4 + (c & 3) * 64;
      for (int o = 0; o < 64; ++o) acc = fmaf(wp[o], av[o], acc);
    }
    Wlr1[i] = f2bf(acc);
  } else if (idx < S7) {
    int i = idx - S6; int c = i / HID4, k = i - c * HID4;
    float acc = 0.f;
    if (c < 8) {
      const float* av = (c < 4) ? al2 + (c & 3) * 64 : ar2 + (c & 3) * 64;
      const float* wp = W2 + (size_t)k * HID4 + (c & 3) * 64;
      for (int o = 0; o < 64; ++o) acc = fmaf(wp[o], av[o], acc);
    }
    Wlr2[i] = f2bf(acc);
  }
}

// ---------------------- fused encoder+layer0 GEMM: Qb = nf@Wcomb + bcomb
// 128x128 tile per block, grid (782, 2); fp32 A converted during staging.
// el/er emitted as MFMA columns (+elc consts) by bcol==0, wc==0 waves.
__global__ __launch_bounds__(256) void k_gemm0(const float* __restrict__ nf,
                                               const ushort* __restrict__ Bt,
                                               const ushort* __restrict__ Wlr,
                                               const float* __restrict__ bcomb,
                                               const float* __restrict__ elc,
                                               ushort* __restrict__ Cb,
                                               float* __restrict__ el,
                                               float* __restrict__ er) {
  __shared__ ushort As[128][104];
  __shared__ ushort Bs[128][104];
  int t = threadIdx.x;
  int lane = t & 63;
  int wid = t >> 6;
  int wr = wid >> 1, wc = wid & 1;
  int brow = blockIdx.x * 128;
  int bcol = blockIdx.y * 128;

  // stage A: fp32 -> bf16 (zero-pad cols >= 74 and OOB rows)
  for (int i = t; i < 128 * ENC_KP; i += 256) {
    int r = i / ENC_KP;
    int c = i - r * ENC_KP;
    int gr = brow + r;
    float v = 0.f;
    if (gr < N_NODES && c < F_IN) v = nf[(size_t)gr * F_IN + c];
    As[r][c] = f2bf(v);
  }
  // stage B: rows bcol..bcol+127 of Wcomb[256][96]
  {
    int r = t >> 1;
    int o = (t & 1) * 48;
#pragma unroll
    for (int i = 0; i < 6; ++i)
      *(int4*)&Bs[r][o + i * 8] =
          *(const int4*)(Bt + (size_t)(bcol + r) * ENC_KP + o + i * 8);
  }
  __syncthreads();

  int fr = lane & 15;
  int ko = (lane >> 4) * 8;
  bool do_lr = (bcol == 0) && (wc == 0);

  f32x4 acc[4][4];
#pragma unroll
  for (int m = 0; m < 4; ++m)
#pragma unroll
    for (int n = 0; n < 4; ++n) acc[m][n] = (f32x4)(0.f);
  f32x4 acc_lr[4];
#pragma unroll
  for (int m = 0; m < 4; ++m) acc_lr[m] = (f32x4)(0.f);

#pragma unroll
  for (int ks = 0; ks < 3; ++ks) {
    short8 a[4], b[4];
#pragma unroll
    for (int m = 0; m < 4; ++m)
      a[m] = *(const short8*)&As[wr * 64 + m * 16 + fr][ks * 32 + ko];
#pragma unroll
    for (int n = 0; n < 4; ++n)
      b[n] = *(const short8*)&Bs[wc * 64 + n * 16 + fr][ks * 32 + ko];
#pragma unroll
    for (int m = 0; m < 4; ++m)
#pragma unroll
      for (int n = 0; n < 4; ++n)
        acc[m][n] = __builtin_amdgcn_mfma_f32_16x16x32_bf16(a[m], b[n], acc[m][n], 0, 0, 0);
    if (do_lr) {
      short8 blr = *(const short8*)(Wlr + (size_t)fr * ENC_KP + ks * 32 + ko);
#pragma unroll
      for (int m = 0; m < 4; ++m)
        acc_lr[m] = __builtin_amdgcn_mfma_f32_16x16x32_bf16(a[m], blr, acc_lr[m], 0, 0, 0);
    }
  }

  int r0 = (lane >> 4) * 4;
  int cc = lane & 15;
#pragma unroll
  for (int m = 0; m < 4; ++m) {
#pragma unroll
    for (int j = 0; j < 4; ++j) {
      int row = brow + wr * 64 + m * 16 + r0 + j;
      if (row >= N_NODES) continue;
#pragma unroll
      for (int n = 0; n < 4; ++n) {
        int col = bcol + wc * 64 + n * 16 + cc;
        Cb[(size_t)row * HID4 + col] = f2bf(acc[m][n][j] + bcomb[col]);
      }
    }
  }
  if (do_lr && cc < 8) {
    float ec = elc[cc];
#pragma unroll
    for (int m = 0; m < 4; ++m)
#pragma unroll
      for (int j = 0; j < 4; ++j) {
        int row = brow + wr * 64 + m * 16 + r0 + j;
        if (row >= N_NODES) continue;
        float v = acc_lr[m][j] + ec;
        if (cc < 4) el[(size_t)row * NHEAD + cc] = v;
        else er[(size_t)row * NHEAD + (cc - 4)] = v;
      }
  }
}

// ---------------------------------------------------------- bf16 MFMA GEMM
// 128x128 tile, 4 waves, dbuf LDS via global_load_lds, XCD-pairing 1D grid.
// el/er fused as MFMA columns (no shuffle epilogue).
template <int K>
__global__ __launch_bounds__(256) void k_gemm_mfma(const ushort* __restrict__ A,
                                                   const ushort* __restrict__ Bt,
                                                   const ushort* __restrict__ Wlr,
                                                   ushort* __restrict__ Cb,
                                                   float* __restrict__ el,
                                                   float* __restrict__ er,
                                                   int n_rows) {
  __shared__ __align__(16) ushort As[2][128 * 32];
  __shared__ __align__(16) ushort Bs[2][128 * 32];
  int bid = blockIdx.x;
  int rpan = (bid >> 4) * 8 + (bid & 7);
  int nrp = (n_rows + 127) / 128;
  if (rpan >= nrp) return;
  int brow = rpan * 128;
  int bcol = ((bid >> 3) & 1) * 128;

  int t = threadIdx.x;
  int lane = t & 63;
  int wid = t >> 6;
  int wr = wid >> 1, wc = wid & 1;

  f32x4 acc[4][4];
#pragma unroll
  for (int m = 0; m < 4; ++m)
#pragma unroll
    for (int n = 0; n < 4; ++n) acc[m][n] = (f32x4)(0.f);

  int srow0 = (wid * 2 + 0) * 16 + (lane >> 2);
  int srow1 = (wid * 2 + 1) * 16 + (lane >> 2);
  int skc = (lane & 3) * 8;
  int ga0 = brow + srow0; if (ga0 > n_rows - 1) ga0 = n_rows - 1;
  int ga1 = brow + srow1; if (ga1 > n_rows - 1) ga1 = n_rows - 1;
  const ushort* pa0 = A + (size_t)ga0 * K + skc;
  const ushort* pa1 = A + (size_t)ga1 * K + skc;
  const ushort* pb0 = Bt + (size_t)(bcol + srow0) * K + skc;
  const ushort* pb1 = Bt + (size_t)(bcol + srow1) * K + skc;
  int lo0 = (wid * 2 + 0) * 512;
  int lo1 = (wid * 2 + 1) * 512;

  int fr = lane & 15;
  int ko = (lane >> 4) * 8;

  bool do_lr = (bcol == 0) && (wc == 0);
  short8 blrr[K / 32];
  f32x4 acc_lr[4];
#pragma unroll
  for (int m = 0; m < 4; ++m) acc_lr[m] = (f32x4)(0.f);
  if (do_lr) {
#pragma unroll
    for (int ks = 0; ks < K / 32; ++ks)
      blrr[ks] = *(const short8*)(Wlr + (size_t)fr * K + ks * 32 + ko);
  }

  glds16(pa0, &As[0][lo0]);
  glds16(pa1, &As[0][lo1]);
  glds16(pb0, &Bs[0][lo0]);
  glds16(pb1, &Bs[0][lo1]);
  __syncthreads();

#pragma unroll
  for (int kstep = 0; kstep < K / 32; ++kstep) {
    int k0 = kstep * 32;
    int cur = kstep & 1;
    if (k0 + 32 < K) {
      glds16(pa0 + k0 + 32, &As[cur ^ 1][lo0]);
      glds16(pa1 + k0 + 32, &As[cur ^ 1][lo1]);
      glds16(pb0 + k0 + 32, &Bs[cur ^ 1][lo0]);
      glds16(pb1 + k0 + 32, &Bs[cur ^ 1][lo1]);
    }
    short8 a[4], b[4];
#pragma unroll
    for (int m = 0; m < 4; ++m)
      a[m] = *(const short8*)(&As[cur][0] + (wr * 64 + m * 16 + fr) * 32 + ko);
#pragma unroll
    for (int n = 0; n < 4; ++n)
      b[n] = *(const short8*)(&Bs[cur][0] + (wc * 64 + n * 16 + fr) * 32 + ko);
#pragma unroll
    for (int m = 0; m < 4; ++m)
#pragma unroll
      for (int n = 0; n < 4; ++n)
        acc[m][n] = __builtin_amdgcn_mfma_f32_16x16x32_bf16(a[m], b[n], acc[m][n], 0, 0, 0);
    if (do_lr) {
#pragma unroll
      for (int m = 0; m < 4; ++m)
        acc_lr[m] = __builtin_amdgcn_mfma_f32_16x16x32_bf16(a[m], blrr[kstep], acc_lr[m], 0, 0, 0);
    }
    __syncthreads();
  }

  int r0 = (lane >> 4) * 4;
  int cc = lane & 15;
#pragma unroll
  for (int m = 0; m < 4; ++m) {
#pragma unroll
    for (int j = 0; j < 4; ++j) {
      int row = brow + wr * 64 + m * 16 + r0 + j;
      if (row >= n_rows) continue;
#pragma unroll
      for (int n = 0; n < 4; ++n)
        Cb[(size_t)row * HID4 + bcol + wc * 64 + n * 16 + cc] = f2bf(acc[m][n][j]);
    }
  }
  if (do_lr && cc < 8) {
#pragma unroll
    for (int m = 0; m < 4; ++m)
#pragma unroll
      for (int j = 0; j < 4; ++j) {
        int row = brow + wr * 64 + m * 16 + r0 + j;
        if (row >= n_rows) continue;
        float v = acc_lr[m][j];
        if (cc < 4) el[(size_t)row * NHEAD + cc] = v;
        else er[(size_t)row * NHEAD + (cc - 4)] = v;
      }
  }
}

// ---------- shift-free softmax aggregate: 4 nodes/wave, 16 lanes per node
__global__ __launch_bounds__(256) void k_agg(const ushort* __restrict__ zb,
                                             const float* __restrict__ el,
                                             const float* __restrict__ er,
                                             const int* __restrict__ off,
                                             const int* __restrict__ srcs,
                                             const float* __restrict__ bias,
                                             ushort* __restrict__ outb) {
  int w = (blockIdx.x * 256 + threadIdx.x) >> 6;
  int lane = threadIdx.x & 63;
  int n = w * 4 + (lane >> 4);
  int li = lane & 15;
  if (n >= N_NODES) return;
  int h = li >> 2;   // head (4 lanes per head)
  int c = li * 16;   // feature base, 16 bf16 per lane
  int beg = off[n], end = off[n + 1];
  float erh = er[(size_t)n * NHEAD + h];

  float s = 0.f;
  float acc[16];
#pragma unroll
  for (int j = 0; j < 16; ++j) acc[j] = 0.f;

  float e0 = 0.f, e1 = 0.f, e2 = 0.f;
  int4 za0 = make_int4(0, 0, 0, 0), zb0 = za0;
  int4 za1 = za0, zb1 = za0, za2 = za0, zb2 = za0;
  if (beg < end) {
    int sn = srcs[beg];
    e0 = el[(size_t)sn * NHEAD + h];
    const ushort* zp = zb + (size_t)sn * HID4 + c;
    za0 = *(const int4*)zp; zb0 = *(const int4*)(zp + 8);
  }
  if (beg + 1 < end) {
    int sn = srcs[beg + 1];
    e1 = el[(size_t)sn * NHEAD + h];
    const ushort* zp = zb + (size_t)sn * HID4 + c;
    za1 = *(const int4*)zp; zb1 = *(const int4*)(zp + 8);
  }
  if (beg + 2 < end) {
    int sn = srcs[beg + 2];
    e2 = el[(size_t)sn * NHEAD + h];
    const ushort* zp = zb + (size_t)sn * HID4 + c;
    za2 = *(const int4*)zp; zb2 = *(const int4*)(zp + 8);
  }

  for (int p = beg; p < end; ++p) {
    float ev = e0;
    int4 va = za0, vb = zb0;
    e0 = e1; za0 = za1; zb0 = zb1;
    e1 = e2; za1 = za2; zb1 = zb2;
    if (p + 3 < end) {
      int sn = srcs[p + 3];
      e2 = el[(size_t)sn * NHEAD + h];
      const ushort* zp = zb + (size_t)sn * HID4 + c;
      za2 = *(const int4*)zp; zb2 = *(const int4*)(zp + 8);
    }
    float pv = __expf(leaky(ev + erh));
    s += pv;
    const ushort* ua = (const ushort*)&va;
    const ushort* ub = (const ushort*)&vb;
#pragma unroll
    for (int j = 0; j < 8; ++j) acc[j] = fmaf(pv, bf2f(ua[j]), acc[j]);
#pragma unroll
    for (int j = 0; j < 8; ++j) acc[8 + j] = fmaf(pv, bf2f(ub[j]), acc[8 + j]);
  }
  float inv = (s > 0.f) ? 1.f / s : 0.f;
  float bb[16];
#pragma unroll
  for (int j = 0; j < 16; j += 4) {
    float4 b4 = *(const float4*)(bias + c + j);
    bb[j] = b4.x; bb[j + 1] = b4.y; bb[j + 2] = b4.z; bb[j + 3] = b4.w;
  }
  int4 ov0, ov1;
  ushort* os0 = (ushort*)&ov0;
  ushort* os1 = (ushort*)&ov1;
#pragma unroll
  for (int j = 0; j < 8; ++j) os0[j] = f2bf(fmaxf(acc[j] * inv + bb[j], 0.f));
#pragma unroll
  for (int j = 0; j < 8; ++j) os1[j] = f2bf(fmaxf(acc[8 + j] * inv + bb[8 + j], 0.f));
  ushort* op = outb + (size_t)n * HID4 + c;
  *(int4*)op = ov0;
  *(int4*)(op + 8) = ov1;
}

// ---------------------------------------------------------------- readout
__global__ __launch_bounds__(256) void k_pool_mlp(const ushort* __restrict__ h,
                                                  const float* __restrict__ r1W,
                                                  const float* __restrict__ r1b,
                                                  const float* __restrict__ r2W,
                                                  const float* __restrict__ r2b,
                                                  float* __restrict__ out) {
  __shared__ float pooled[3 * HID4];
  __shared__ float part[4][HID];
  __shared__ float mid[HID];
  int g = blockIdx.x;
  int t = threadIdx.x;
  const ushort* base = h + (size_t)g * NODES_PER_G * HID4;
  float sum = 0.f, mx = -1e30f;
  for (int i = 0; i < NODES_PER_G; ++i) {
    float v = bf2f(base[(size_t)i * HID4 + t]);
    sum += v;
    mx = fmaxf(mx, v);
  }
  pooled[t] = sum / (float)NODES_PER_G;
  pooled[HID4 + t] = mx;
  pooled[2 * HID4 + t] = sum;
  __syncthreads();
  {
    int o = t & 63, chunk = t >> 6;
    float acc = 0.f;
    int k0 = chunk * 192;
    for (int k = k0; k < k0 + 192; ++k) acc = fmaf(pooled[k], r1W[k * HID + o], acc);
    part[chunk][o] = acc;
  }
  __syncthreads();
  if (t < HID) {
    float acc = r1b[t] + part[0][t] + part[1][t] + part[2][t] + part[3][t];
    mid[t] = fmaxf(acc, 0.f);
  }
  __syncthreads();
  if (t < OUT_DIM) {
    float acc = r2b[t];
    for (int k = 0; k < HID; ++k) acc = fmaf(mid[k], r2W[k * OUT_DIM + t], acc);
    out[(size_t)g * OUT_DIM + t] = acc;
  }
}

// ---------------------------------------------------------------- launch
extern "C" void kernel_launch(void* const* d_in, const int* in_sizes, int n_in,
                              void* d_out, int out_size, void* d_ws, size_t ws_size,
                              hipStream_t stream) {
  const float* node_feat = (const float*)d_in[0];
  const int* src = (const int*)d_in[1];
  const int* dst = (const int*)d_in[2];
  const float* enc_W = (const float*)d_in[4];
  const float* enc_b = (const float*)d_in[5];
  const float* Wl[3] = {(const float*)d_in[6], (const float*)d_in[10], (const float*)d_in[14]};
  const float* all_[3] = {(const float*)d_in[7], (const float*)d_in[11], (const float*)d_in[15]};
  const float* arl[3] = {(const float*)d_in[8], (const float*)d_in[12], (const float*)d_in[16]};
  const float* bl[3] = {(const float*)d_in[9], (const float*)d_in[13], (const float*)d_in[17]};
  const float* r1W = (const float*)d_in[18];
  const float* r1b = (const float*)d_in[19];
  const float* r2W = (const float*)d_in[20];
  const float* r2b = (const float*)d_in[21];
  float* out = (float*)d_out;

  char* p = (char*)d_ws;
  auto alloc = [&](size_t bytes) {
    void* r = (void*)p;
    p += (bytes + 255) & ~(size_t)255;
    return r;
  };
  int* off = (int*)alloc((N_NODES + 1) * sizeof(int));
  int* cursor = (int*)alloc(N_NODES * sizeof(int));
  int* srcs = (int*)alloc(N_EDGES * sizeof(int));
  int* blksum = (int*)alloc(256 * sizeof(int));
  float* el = (float*)alloc((size_t)N_NODES * NHEAD * sizeof(float));
  float* er = (float*)alloc((size_t)N_NODES * NHEAD * sizeof(float));
  ushort* Qb = (ushort*)alloc((size_t)N_NODES * HID4 * sizeof(ushort));
  ushort* Pb = (ushort*)alloc((size_t)N_NODES * HID4 * sizeof(ushort));
  ushort* Wcomb = (ushort*)alloc((size_t)HID4 * ENC_KP * sizeof(ushort));
  float* bcomb = (float*)alloc((size_t)HID4 * sizeof(float));
  ushort* Wlrc = (ushort*)alloc((size_t)16 * ENC_KP * sizeof(ushort));
  float* elc = (float*)alloc(8 * sizeof(float));
  ushort* Wt1 = (ushort*)alloc((size_t)HID4 * HID4 * sizeof(ushort));
  ushort* Wt2 = (ushort*)alloc((size_t)HID4 * HID4 * sizeof(ushort));
  ushort* Wlr1 = (ushort*)alloc((size_t)16 * HID4 * sizeof(ushort));
  ushort* Wlr2 = (ushort*)alloc((size_t)16 * HID4 * sizeof(ushort));

  // ---- CSR build (deterministic via per-segment value sort)
  hipMemsetAsync(off, 0, (N_NODES + 1) * sizeof(int), stream);
  hipMemsetAsync(cursor, 0, N_NODES * sizeof(int), stream);
  k_count<<<(N_EDGES + 255) / 256, 256, 0, stream>>>(dst, off);
  const int SCAN_N = N_NODES + 1;
  const int NB = (SCAN_N + 1023) / 1024;
  k_scan1<<<NB, 256, 0, stream>>>(off, SCAN_N, blksum);
  k_scan2<<<1, 256, 0, stream>>>(blksum, NB);
  k_scan3<<<NB, 256, 0, stream>>>(off, SCAN_N, blksum);
  k_scatter<<<(N_EDGES + 255) / 256, 256, 0, stream>>>(dst, src, off, cursor, srcs);
  k_sortseg<<<(N_NODES + 255) / 256, 256, 0, stream>>>(off, srcs);

  // ---- all weight prep in one launch
  const int PREP_N = HID4 * ENC_KP + HID4 + 16 * ENC_KP + 8 +
                     2 * HID4 * HID4 + 2 * 16 * HID4;
  k_prep<<<(PREP_N + 255) / 256, 256, 0, stream>>>(
      enc_W, enc_b, Wl[0], Wl[1], Wl[2],
      all_[0], arl[0], all_[1], arl[1], all_[2], arl[2],
      Wcomb, bcomb, Wlrc, elc, Wt1, Wt2, Wlr1, Wlr2);

  // ---- fused encoder+layer0 GEMM -> Qb, el, er ; then agg layer 0
  const int NRP = (N_NODES + 127) / 128;
  const int AGG_BLOCKS = ((N_NODES + 3) / 4 + 3) / 4;
  dim3 g0grid(NRP, 2);
  k_gemm0<<<g0grid, 256, 0, stream>>>(node_feat, Wcomb, Wlrc, bcomb, elc, Qb, el, er);
  k_agg<<<AGG_BLOCKS, 256, 0, stream>>>(Qb, el, er, off, srcs, bl[0], Pb);

  // ---- layers 1,2: GEMM (+el/er via MFMA) ; agg
  const int GEMM_BLOCKS = ((NRP + 7) / 8) * 16;
  const ushort* Wts[2] = {Wt1, Wt2};
  const ushort* Wlrs[2] = {Wlr1, Wlr2};
  for (int l = 0; l < 2; ++l) {
    k_gemm_mfma<HID4><<<GEMM_BLOCKS, 256, 0, stream>>>(Pb, Wts[l], Wlrs[l], Qb, el, er, N_NODES);
    k_agg<<<AGG_BLOCKS, 256, 0, stream>>>(Qb, el, er, off, srcs, bl[l + 1], Pb);
  }

  // ---- readout
  k_pool_mlp<<<N_GRAPHS, 256, 0, stream>>>(Pb, r1W, r1b, r2W, r2b, out);
}

// Round 16
// 418.951 us; speedup vs baseline: 1.1033x; 1.1033x over previous
//
#include <hip/hip_runtime.h>

#define N_NODES 100000
#define N_EDGES 400000
#define N_GRAPHS 2000
#define F_IN 74
#define ENC_KP 96
#define HID 64
#define NHEAD 4
#define HID4 256
#define OUT_DIM 128
#define NODES_PER_G 50

typedef __attribute__((ext_vector_type(8))) short short8;
typedef __attribute__((ext_vector_type(4))) float f32x4;

__device__ inline ushort f2bf(float f) {
  union { float f; unsigned u; } v; v.f = f;
  unsigned u = v.u;
  return (ushort)((u + 0x7FFFu + ((u >> 16) & 1u)) >> 16);
}
__device__ inline float bf2f(ushort b) {
  union { unsigned u; float f; } v; v.u = ((unsigned)b) << 16;
  return v.f;
}
__device__ inline float leaky(float x) { return x >= 0.f ? x : 0.2f * x; }

// async global->LDS, 16B per lane, dest = uniform base + lane*16
__device__ inline void glds16(const ushort* g, ushort* l) {
  __builtin_amdgcn_global_load_lds(
      (const __attribute__((address_space(1))) void*)g,
      (__attribute__((address_space(3))) void*)l, 16, 0, 0);
}

// ---------------------------------------------------------------- CSR build
__global__ __launch_bounds__(256) void k_count(const int* __restrict__ dst,
                                               int* __restrict__ off) {
  int e = blockIdx.x * 256 + threadIdx.x;
  if (e < N_EDGES) atomicAdd(&off[dst[e] + 1], 1);
}

__global__ __launch_bounds__(256) void k_scan1(int* __restrict__ data, int n,
                                               int* __restrict__ blksum) {
  __shared__ int sh[256];
  int t = threadIdx.x;
  int base = blockIdx.x * 1024 + t * 4;
  int v0 = (base + 0 < n) ? data[base + 0] : 0;
  int v1 = (base + 1 < n) ? data[base + 1] : 0;
  int v2 = (base + 2 < n) ? data[base + 2] : 0;
  int v3 = (base + 3 < n) ? data[base + 3] : 0;
  v1 += v0; v2 += v1; v3 += v2;
  int tot = v3;
  sh[t] = tot;
  __syncthreads();
  for (int o = 1; o < 256; o <<= 1) {
    int x = (t >= o) ? sh[t - o] : 0;
    __syncthreads();
    sh[t] += x;
    __syncthreads();
  }
  int excl = sh[t] - tot;
  if (base + 0 < n) data[base + 0] = v0 + excl;
  if (base + 1 < n) data[base + 1] = v1 + excl;
  if (base + 2 < n) data[base + 2] = v2 + excl;
  if (base + 3 < n) data[base + 3] = v3 + excl;
  if (t == 255) blksum[blockIdx.x] = sh[255];
}

__global__ __launch_bounds__(256) void k_scan2(int* __restrict__ blksum, int nb) {
  __shared__ int sh[256];
  int t = threadIdx.x;
  sh[t] = (t < nb) ? blksum[t] : 0;
  __syncthreads();
  for (int o = 1; o < 256; o <<= 1) {
    int x = (t >= o) ? sh[t - o] : 0;
    __syncthreads();
    sh[t] += x;
    __syncthreads();
  }
  if (t < nb) blksum[t] = sh[t];
}

__global__ __launch_bounds__(256) void k_scan3(int* __restrict__ data, int n,
                                               const int* __restrict__ blksum) {
  int b = blockIdx.x;
  if (b == 0) return;
  int add = blksum[b - 1];
  int base = b * 1024 + threadIdx.x * 4;
  for (int j = 0; j < 4; ++j)
    if (base + j < n) data[base + j] += add;
}

__global__ __launch_bounds__(256) void k_scatter(const int* __restrict__ dst,
                                                 const int* __restrict__ src,
                                                 const int* __restrict__ off,
                                                 int* __restrict__ cursor,
                                                 int* __restrict__ srcs) {
  int e = blockIdx.x * 256 + threadIdx.x;
  if (e >= N_EDGES) return;
  int d = dst[e];
  int pos = off[d] + atomicAdd(&cursor[d], 1);
  srcs[pos] = src[e];
}

__global__ __launch_bounds__(256) void k_sortseg(const int* __restrict__ off,
                                                 int* __restrict__ srcs) {
  int n = blockIdx.x * 256 + threadIdx.x;
  if (n >= N_NODES) return;
  int beg = off[n], end = off[n + 1];
  for (int i = beg + 1; i < end; ++i) {
    int key = srcs[i];
    int j = i - 1;
    while (j >= beg && srcs[j] > key) { srcs[j + 1] = srcs[j]; --j; }
    srcs[j + 1] = key;
  }
}

// -------------------------------------------- nf fp32 [N,74] -> bf16 [N,96]
__global__ __launch_bounds__(256) void k_pad_nf(const float* __restrict__ nf,
                                                ushort* __restrict__ nfb) {
  long long idx = (long long)blockIdx.x * 256 + threadIdx.x;
  if (idx >= (long long)N_NODES * ENC_KP) return;
  int n = (int)(idx / ENC_KP);
  int c = (int)(idx - (long long)n * ENC_KP);
  ushort v = 0;
  if (c < F_IN) v = f2bf(nf[(size_t)n * F_IN + c]);
  nfb[idx] = v;
}

// ------------------------- consolidated weight prep (one launch, upfront)
// Fused encoder+layer0: Wcomb[256][96] = (We@W0)^T, bcomb[256] = be@W0,
// Wlrc[16][96] = (We_pad @ (W0@al|ar))^T, elc[8] = be@(W0@al|ar).
// Layers 1,2: Wt_l [256][256]; Wlr_l [16][256].
__global__ __launch_bounds__(256) void k_prep(
    const float* __restrict__ enc_W, const float* __restrict__ enc_b,
    const float* __restrict__ W0, const float* __restrict__ W1,
    const float* __restrict__ W2,
    const float* __restrict__ al0, const float* __restrict__ ar0,
    const float* __restrict__ al1, const float* __restrict__ ar1,
    const float* __restrict__ al2, const float* __restrict__ ar2,
    ushort* __restrict__ Wcomb, float* __restrict__ bcomb,
    ushort* __restrict__ Wlrc, float* __restrict__ elc,
    ushort* __restrict__ Wt1, ushort* __restrict__ Wt2,
    ushort* __restrict__ Wlr1, ushort* __restrict__ Wlr2) {
  const int S0 = HID4 * ENC_KP;          // Wcomb
  const int S1 = S0 + HID4;              // bcomb
  const int S2 = S1 + 16 * ENC_KP;       // Wlrc
  const int S3 = S2 + 8;                 // elc
  const int S4 = S3 + HID4 * HID4;       // Wt1
  const int S5 = S4 + HID4 * HID4;       // Wt2
  const int S6 = S5 + 16 * HID4;         // Wlr1
  const int S7 = S6 + 16 * HID4;         // Wlr2
  int idx = blockIdx.x * 256 + threadIdx.x;
  if (idx < S0) {
    int c = idx / ENC_KP, k = idx - c * ENC_KP;
    float acc = 0.f;
    if (k < F_IN) {
      const float* we = enc_W + (size_t)k * HID;
      for (int o = 0; o < HID; ++o) acc = fmaf(we[o], W0[(size_t)o * HID4 + c], acc);
    }
    Wcomb[idx] = f2bf(acc);
  } else if (idx < S1) {
    int c = idx - S0;
    float acc = 0.f;
    for (int o = 0; o < HID; ++o) acc = fmaf(enc_b[o], W0[(size_t)o * HID4 + c], acc);
    bcomb[c] = acc;
  } else if (idx < S2) {
    int i = idx - S1;
    int c = i / ENC_KP, k = i - c * ENC_KP;
    float acc = 0.f;
    if (c < 8 && k < F_IN) {
      const float* av = (c < 4) ? al0 + (c & 3) * 64 : ar0 + (c & 3) * 64;
      const float* we = enc_W + (size_t)k * HID;
      for (int o = 0; o < HID; ++o) {
        float w = 0.f;
        const float* wp = W0 + (size_t)o * HID4 + (c & 3) * 64;
        for (int j = 0; j < 64; ++j) w = fmaf(wp[j], av[j], w);
        acc = fmaf(we[o], w, acc);
      }
    }
    Wlrc[i] = f2bf(acc);
  } else if (idx < S3) {
    int c = idx - S2;
    float acc = 0.f;
    const float* av = (c < 4) ? al0 + (c & 3) * 64 : ar0 + (c & 3) * 64;
    for (int o = 0; o < HID; ++o) {
      float w = 0.f;
      const float* wp = W0 + (size_t)o * HID4 + (c & 3) * 64;
      for (int j = 0; j < 64; ++j) w = fmaf(wp[j], av[j], w);
      acc = fmaf(enc_b[o], w, acc);
    }
    elc[c] = acc;
  } else if (idx < S4) {
    int i = idx - S3; int k = i >> 8, n = i & 255;
    Wt1[(size_t)n * HID4 + k] = f2bf(W1[i]);
  } else if (idx < S5) {
    int i = idx - S4; int k = i >> 8, n = i & 255;
    Wt2[(size_t)n * HID4 + k] = f2bf(W2[i]);
  } else if (idx < S6) {
    int i = idx - S5; int c = i / HID4, k = i - c * HID4;
    float acc = 0.f;
    if (c < 8) {
      const float* av = (c < 4) ? al1 + (c & 3) * 64 : ar1 + (c & 3) * 64;
      const float* wp = W1 + (size_t)k * HID4 + (c & 3) * 64;
      for (int o = 0; o < 64; ++o) acc = fmaf(wp[o], av[o], acc);
    }
    Wlr1[i] = f2bf(acc);
  } else if (idx < S7) {
    int i = idx - S6; int c = i / HID4, k = i - c * HID4;
    float acc = 0.f;
    if (c < 8) {
      const float* av = (c < 4) ? al2 + (c & 3) * 64 : ar2 + (c & 3) * 64;
      const float* wp = W2 + (size_t)k * HID4 + (c & 3) * 64;
      for (int o = 0; o < 64; ++o) acc = fmaf(wp[o], av[o], acc);
    }
    Wlr2[i] = f2bf(acc);
  }
}

// ---------------------------------------------------------- bf16 MFMA GEMM
// 128x128 tile, 4 waves, dbuf LDS via global_load_lds, XCD-pairing 1D grid.
// el/er fused as MFMA columns (no shuffle epilogue). BIAS variant adds
// bcomb[col] to C and elc[cc] to el/er (fused encoder+layer0 path).
template <int K, bool BIAS>
__global__ __launch_bounds__(256) void k_gemm_mfma(const ushort* __restrict__ A,
                                                   const ushort* __restrict__ Bt,
                                                   const ushort* __restrict__ Wlr,
                                                   const float* __restrict__ bcomb,
                                                   const float* __restrict__ elc,
                                                   ushort* __restrict__ Cb,
                                                   float* __restrict__ el,
                                                   float* __restrict__ er,
                                                   int n_rows) {
  __shared__ __align__(16) ushort As[2][128 * 32];
  __shared__ __align__(16) ushort Bs[2][128 * 32];
  int bid = blockIdx.x;
  int rpan = (bid >> 4) * 8 + (bid & 7);
  int nrp = (n_rows + 127) / 128;
  if (rpan >= nrp) return;
  int brow = rpan * 128;
  int bcol = ((bid >> 3) & 1) * 128;

  int t = threadIdx.x;
  int lane = t & 63;
  int wid = t >> 6;
  int wr = wid >> 1, wc = wid & 1;

  f32x4 acc[4][4];
#pragma unroll
  for (int m = 0; m < 4; ++m)
#pragma unroll
    for (int n = 0; n < 4; ++n) acc[m][n] = (f32x4)(0.f);

  int srow0 = (wid * 2 + 0) * 16 + (lane >> 2);
  int srow1 = (wid * 2 + 1) * 16 + (lane >> 2);
  int skc = (lane & 3) * 8;
  int ga0 = brow + srow0; if (ga0 > n_rows - 1) ga0 = n_rows - 1;
  int ga1 = brow + srow1; if (ga1 > n_rows - 1) ga1 = n_rows - 1;
  const ushort* pa0 = A + (size_t)ga0 * K + skc;
  const ushort* pa1 = A + (size_t)ga1 * K + skc;
  const ushort* pb0 = Bt + (size_t)(bcol + srow0) * K + skc;
  const ushort* pb1 = Bt + (size_t)(bcol + srow1) * K + skc;
  int lo0 = (wid * 2 + 0) * 512;
  int lo1 = (wid * 2 + 1) * 512;

  int fr = lane & 15;
  int ko = (lane >> 4) * 8;

  bool do_lr = (bcol == 0) && (wc == 0);
  short8 blrr[K / 32];
  f32x4 acc_lr[4];
#pragma unroll
  for (int m = 0; m < 4; ++m) acc_lr[m] = (f32x4)(0.f);
  if (do_lr) {
#pragma unroll
    for (int ks = 0; ks < K / 32; ++ks)
      blrr[ks] = *(const short8*)(Wlr + (size_t)fr * K + ks * 32 + ko);
  }

  glds16(pa0, &As[0][lo0]);
  glds16(pa1, &As[0][lo1]);
  glds16(pb0, &Bs[0][lo0]);
  glds16(pb1, &Bs[0][lo1]);
  __syncthreads();

#pragma unroll
  for (int kstep = 0; kstep < K / 32; ++kstep) {
    int k0 = kstep * 32;
    int cur = kstep & 1;
    if (k0 + 32 < K) {
      glds16(pa0 + k0 + 32, &As[cur ^ 1][lo0]);
      glds16(pa1 + k0 + 32, &As[cur ^ 1][lo1]);
      glds16(pb0 + k0 + 32, &Bs[cur ^ 1][lo0]);
      glds16(pb1 + k0 + 32, &Bs[cur ^ 1][lo1]);
    }
    short8 a[4], b[4];
#pragma unroll
    for (int m = 0; m < 4; ++m)
      a[m] = *(const short8*)(&As[cur][0] + (wr * 64 + m * 16 + fr) * 32 + ko);
#pragma unroll
    for (int n = 0; n < 4; ++n)
      b[n] = *(const short8*)(&Bs[cur][0] + (wc * 64 + n * 16 + fr) * 32 + ko);
#pragma unroll
    for (int m = 0; m < 4; ++m)
#pragma unroll
      for (int n = 0; n < 4; ++n)
        acc[m][n] = __builtin_amdgcn_mfma_f32_16x16x32_bf16(a[m], b[n], acc[m][n], 0, 0, 0);
    if (do_lr) {
#pragma unroll
      for (int m = 0; m < 4; ++m)
        acc_lr[m] = __builtin_amdgcn_mfma_f32_16x16x32_bf16(a[m], blrr[kstep], acc_lr[m], 0, 0, 0);
    }
    __syncthreads();
  }

  int r0 = (lane >> 4) * 4;
  int cc = lane & 15;
  float bc[4];
  if constexpr (BIAS) {
#pragma unroll
    for (int n = 0; n < 4; ++n) bc[n] = bcomb[bcol + wc * 64 + n * 16 + cc];
  }
#pragma unroll
  for (int m = 0; m < 4; ++m) {
#pragma unroll
    for (int j = 0; j < 4; ++j) {
      int row = brow + wr * 64 + m * 16 + r0 + j;
      if (row >= n_rows) continue;
#pragma unroll
      for (int n = 0; n < 4; ++n) {
        float v = acc[m][n][j];
        if constexpr (BIAS) v += bc[n];
        Cb[(size_t)row * HID4 + bcol + wc * 64 + n * 16 + cc] = f2bf(v);
      }
    }
  }
  if (do_lr && cc < 8) {
    float ec = 0.f;
    if constexpr (BIAS) ec = elc[cc];
#pragma unroll
    for (int m = 0; m < 4; ++m)
#pragma unroll
      for (int j = 0; j < 4; ++j) {
        int row = brow + wr * 64 + m * 16 + r0 + j;
        if (row >= n_rows) continue;
        float v = acc_lr[m][j] + ec;
        if (cc < 4) el[(size_t)row * NHEAD + cc] = v;
        else er[(size_t)row * NHEAD + (cc - 4)] = v;
      }
  }
}

// ---------- shift-free softmax aggregate: 4 nodes/wave, 16 lanes per node
__global__ __launch_bounds__(256) void k_agg(const ushort* __restrict__ zb,
                                             const float* __restrict__ el,
                                             const float* __restrict__ er,
                                             const int* __restrict__ off,
                                             const int* __restrict__ srcs,
                                             const float* __restrict__ bias,
                                             ushort* __restrict__ outb) {
  int w = (blockIdx.x * 256 + threadIdx.x) >> 6;
  int lane = threadIdx.x & 63;
  int n = w * 4 + (lane >> 4);
  int li = lane & 15;
  if (n >= N_NODES) return;
  int h = li >> 2;   // head (4 lanes per head)
  int c = li * 16;   // feature base, 16 bf16 per lane
  int beg = off[n], end = off[n + 1];
  float erh = er[(size_t)n * NHEAD + h];

  float s = 0.f;
  float acc[16];
#pragma unroll
  for (int j = 0; j < 16; ++j) acc[j] = 0.f;

  float e0 = 0.f, e1 = 0.f, e2 = 0.f;
  int4 za0 = make_int4(0, 0, 0, 0), zb0 = za0;
  int4 za1 = za0, zb1 = za0, za2 = za0, zb2 = za0;
  if (beg < end) {
    int sn = srcs[beg];
    e0 = el[(size_t)sn * NHEAD + h];
    const ushort* zp = zb + (size_t)sn * HID4 + c;
    za0 = *(const int4*)zp; zb0 = *(const int4*)(zp + 8);
  }
  if (beg + 1 < end) {
    int sn = srcs[beg + 1];
    e1 = el[(size_t)sn * NHEAD + h];
    const ushort* zp = zb + (size_t)sn * HID4 + c;
    za1 = *(const int4*)zp; zb1 = *(const int4*)(zp + 8);
  }
  if (beg + 2 < end) {
    int sn = srcs[beg + 2];
    e2 = el[(size_t)sn * NHEAD + h];
    const ushort* zp = zb + (size_t)sn * HID4 + c;
    za2 = *(const int4*)zp; zb2 = *(const int4*)(zp + 8);
  }

  for (int p = beg; p < end; ++p) {
    float ev = e0;
    int4 va = za0, vb = zb0;
    e0 = e1; za0 = za1; zb0 = zb1;
    e1 = e2; za1 = za2; zb1 = zb2;
    if (p + 3 < end) {
      int sn = srcs[p + 3];
      e2 = el[(size_t)sn * NHEAD + h];
      const ushort* zp = zb + (size_t)sn * HID4 + c;
      za2 = *(const int4*)zp; zb2 = *(const int4*)(zp + 8);
    }
    float pv = __expf(leaky(ev + erh));
    s += pv;
    const ushort* ua = (const ushort*)&va;
    const ushort* ub = (const ushort*)&vb;
#pragma unroll
    for (int j = 0; j < 8; ++j) acc[j] = fmaf(pv, bf2f(ua[j]), acc[j]);
#pragma unroll
    for (int j = 0; j < 8; ++j) acc[8 + j] = fmaf(pv, bf2f(ub[j]), acc[8 + j]);
  }
  float inv = (s > 0.f) ? 1.f / s : 0.f;
  float bb[16];
#pragma unroll
  for (int j = 0; j < 16; j += 4) {
    float4 b4 = *(const float4*)(bias + c + j);
    bb[j] = b4.x; bb[j + 1] = b4.y; bb[j + 2] = b4.z; bb[j + 3] = b4.w;
  }
  int4 ov0, ov1;
  ushort* os0 = (ushort*)&ov0;
  ushort* os1 = (ushort*)&ov1;
#pragma unroll
  for (int j = 0; j < 8; ++j) os0[j] = f2bf(fmaxf(acc[j] * inv + bb[j], 0.f));
#pragma unroll
  for (int j = 0; j < 8; ++j) os1[j] = f2bf(fmaxf(acc[8 + j] * inv + bb[8 + j], 0.f));
  ushort* op = outb + (size_t)n * HID4 + c;
  *(int4*)op = ov0;
  *(int4*)(op + 8) = ov1;
}

// ---------------------------------------------------------------- readout
__global__ __launch_bounds__(256) void k_pool_mlp(const ushort* __restrict__ h,
                                                  const float* __restrict__ r1W,
                                                  const float* __restrict__ r1b,
                                                  const float* __restrict__ r2W,
                                                  const float* __restrict__ r2b,
                                                  float* __restrict__ out) {
  __shared__ float pooled[3 * HID4];
  __shared__ float part[4][HID];
  __shared__ float mid[HID];
  int g = blockIdx.x;
  int t = threadIdx.x;
  const ushort* base = h + (size_t)g * NODES_PER_G * HID4;
  float sum = 0.f, mx = -1e30f;
  for (int i = 0; i < NODES_PER_G; ++i) {
    float v = bf2f(base[(size_t)i * HID4 + t]);
    sum += v;
    mx = fmaxf(mx, v);
  }
  pooled[t] = sum / (float)NODES_PER_G;
  pooled[HID4 + t] = mx;
  pooled[2 * HID4 + t] = sum;
  __syncthreads();
  {
    int o = t & 63, chunk = t >> 6;
    float acc = 0.f;
    int k0 = chunk * 192;
    for (int k = k0; k < k0 + 192; ++k) acc = fmaf(pooled[k], r1W[k * HID + o], acc);
    part[chunk][o] = acc;
  }
  __syncthreads();
  if (t < HID) {
    float acc = r1b[t] + part[0][t] + part[1][t] + part[2][t] + part[3][t];
    mid[t] = fmaxf(acc, 0.f);
  }
  __syncthreads();
  if (t < OUT_DIM) {
    float acc = r2b[t];
    for (int k = 0; k < HID; ++k) acc = fmaf(mid[k], r2W[k * OUT_DIM + t], acc);
    out[(size_t)g * OUT_DIM + t] = acc;
  }
}

// ---------------------------------------------------------------- launch
extern "C" void kernel_launch(void* const* d_in, const int* in_sizes, int n_in,
                              void* d_out, int out_size, void* d_ws, size_t ws_size,
                              hipStream_t stream) {
  const float* node_feat = (const float*)d_in[0];
  const int* src = (const int*)d_in[1];
  const int* dst = (const int*)d_in[2];
  const float* enc_W = (const float*)d_in[4];
  const float* enc_b = (const float*)d_in[5];
  const float* Wl[3] = {(const float*)d_in[6], (const float*)d_in[10], (const float*)d_in[14]};
  const float* all_[3] = {(const float*)d_in[7], (const float*)d_in[11], (const float*)d_in[15]};
  const float* arl[3] = {(const float*)d_in[8], (const float*)d_in[12], (const float*)d_in[16]};
  const float* bl[3] = {(const float*)d_in[9], (const float*)d_in[13], (const float*)d_in[17]};
  const float* r1W = (const float*)d_in[18];
  const float* r1b = (const float*)d_in[19];
  const float* r2W = (const float*)d_in[20];
  const float* r2b = (const float*)d_in[21];
  float* out = (float*)d_out;

  char* p = (char*)d_ws;
  auto alloc = [&](size_t bytes) {
    void* r = (void*)p;
    p += (bytes + 255) & ~(size_t)255;
    return r;
  };
  int* off = (int*)alloc((N_NODES + 1) * sizeof(int));
  int* cursor = (int*)alloc(N_NODES * sizeof(int));
  int* srcs = (int*)alloc(N_EDGES * sizeof(int));
  int* blksum = (int*)alloc(256 * sizeof(int));
  float* el = (float*)alloc((size_t)N_NODES * NHEAD * sizeof(float));
  float* er = (float*)alloc((size_t)N_NODES * NHEAD * sizeof(float));
  ushort* Qb = (ushort*)alloc((size_t)N_NODES * HID4 * sizeof(ushort));
  ushort* Pb = (ushort*)alloc((size_t)N_NODES * HID4 * sizeof(ushort));
  ushort* nfb = (ushort*)alloc((size_t)N_NODES * ENC_KP * sizeof(ushort));
  ushort* Wcomb = (ushort*)alloc((size_t)HID4 * ENC_KP * sizeof(ushort));
  float* bcomb = (float*)alloc((size_t)HID4 * sizeof(float));
  ushort* Wlrc = (ushort*)alloc((size_t)16 * ENC_KP * sizeof(ushort));
  float* elc = (float*)alloc(8 * sizeof(float));
  ushort* Wt1 = (ushort*)alloc((size_t)HID4 * HID4 * sizeof(ushort));
  ushort* Wt2 = (ushort*)alloc((size_t)HID4 * HID4 * sizeof(ushort));
  ushort* Wlr1 = (ushort*)alloc((size_t)16 * HID4 * sizeof(ushort));
  ushort* Wlr2 = (ushort*)alloc((size_t)16 * HID4 * sizeof(ushort));

  // ---- CSR build (deterministic via per-segment value sort)
  hipMemsetAsync(off, 0, (N_NODES + 1) * sizeof(int), stream);
  hipMemsetAsync(cursor, 0, N_NODES * sizeof(int), stream);
  k_count<<<(N_EDGES + 255) / 256, 256, 0, stream>>>(dst, off);
  const int SCAN_N = N_NODES + 1;
  const int NB = (SCAN_N + 1023) / 1024;
  k_scan1<<<NB, 256, 0, stream>>>(off, SCAN_N, blksum);
  k_scan2<<<1, 256, 0, stream>>>(blksum, NB);
  k_scan3<<<NB, 256, 0, stream>>>(off, SCAN_N, blksum);
  k_scatter<<<(N_EDGES + 255) / 256, 256, 0, stream>>>(dst, src, off, cursor, srcs);
  k_sortseg<<<(N_NODES + 255) / 256, 256, 0, stream>>>(off, srcs);

  // ---- weight prep (one launch) + nf pad/convert
  const int PREP_N = HID4 * ENC_KP + HID4 + 16 * ENC_KP + 8 +
                     2 * HID4 * HID4 + 2 * 16 * HID4;
  k_prep<<<(PREP_N + 255) / 256, 256, 0, stream>>>(
      enc_W, enc_b, Wl[0], Wl[1], Wl[2],
      all_[0], arl[0], all_[1], arl[1], all_[2], arl[2],
      Wcomb, bcomb, Wlrc, elc, Wt1, Wt2, Wlr1, Wlr2);
  k_pad_nf<<<(int)(((long long)N_NODES * ENC_KP + 255) / 256), 256, 0, stream>>>(node_feat, nfb);

  // ---- fused encoder+layer0 GEMM (K=96, dbuf glds16) -> Qb, el, er ; agg
  const int NRP = (N_NODES + 127) / 128;
  const int GEMM_BLOCKS = ((NRP + 7) / 8) * 16;
  const int AGG_BLOCKS = ((N_NODES + 3) / 4 + 3) / 4;
  k_gemm_mfma<ENC_KP, true><<<GEMM_BLOCKS, 256, 0, stream>>>(
      nfb, Wcomb, Wlrc, bcomb, elc, Qb, el, er, N_NODES);
  k_agg<<<AGG_BLOCKS, 256, 0, stream>>>(Qb, el, er, off, srcs, bl[0], Pb);

  // ---- layers 1,2: GEMM (+el/er via MFMA) ; agg
  const ushort* Wts[2] = {Wt1, Wt2};
  const ushort* Wlrs[2] = {Wlr1, Wlr2};
  for (int l = 0; l < 2; ++l) {
    k_gemm_mfma<HID4, false><<<GEMM_BLOCKS, 256, 0, stream>>>(
        Pb, Wts[l], Wlrs[l], nullptr, nullptr, Qb, el, er, N_NODES);
    k_agg<<<AGG_BLOCKS, 256, 0, stream>>>(Qb, el, er, off, srcs, bl[l + 1], Pb);
  }

  // ---- readout
  k_pool_mlp<<<N_GRAPHS, 256, 0, stream>>>(Pb, r1W, r1b, r2W, r2b, out);
}

// Round 17
// 365.552 us; speedup vs baseline: 1.2644x; 1.1461x over previous
//
#include <hip/hip_runtime.h>

#define N_NODES 100000
#define N_EDGES 400000
#define N_GRAPHS 2000
#define F_IN 74
#define ENC_KP 96
#define HID 64
#define NHEAD 4
#define HID4 256
#define OUT_DIM 128
#define NODES_PER_G 50

typedef __attribute__((ext_vector_type(8))) short short8;
typedef __attribute__((ext_vector_type(4))) float f32x4;

__device__ inline ushort f2bf(float f) {
  union { float f; unsigned u; } v; v.f = f;
  unsigned u = v.u;
  return (ushort)((u + 0x7FFFu + ((u >> 16) & 1u)) >> 16);
}
__device__ inline float bf2f(ushort b) {
  union { unsigned u; float f; } v; v.u = ((unsigned)b) << 16;
  return v.f;
}
__device__ inline float leaky(float x) { return x >= 0.f ? x : 0.2f * x; }

// async global->LDS, 16B per lane, dest = uniform base + lane*16
__device__ inline void glds16(const ushort* g, ushort* l) {
  __builtin_amdgcn_global_load_lds(
      (const __attribute__((address_space(1))) void*)g,
      (__attribute__((address_space(3))) void*)l, 16, 0, 0);
}

// ---------------------------------------------------------------- CSR build
__global__ __launch_bounds__(256) void k_count(const int* __restrict__ dst,
                                               int* __restrict__ off) {
  int e = blockIdx.x * 256 + threadIdx.x;
  if (e < N_EDGES) atomicAdd(&off[dst[e] + 1], 1);
}

__global__ __launch_bounds__(256) void k_scan1(int* __restrict__ data, int n,
                                               int* __restrict__ blksum) {
  __shared__ int sh[256];
  int t = threadIdx.x;
  int base = blockIdx.x * 1024 + t * 4;
  int v0 = (base + 0 < n) ? data[base + 0] : 0;
  int v1 = (base + 1 < n) ? data[base + 1] : 0;
  int v2 = (base + 2 < n) ? data[base + 2] : 0;
  int v3 = (base + 3 < n) ? data[base + 3] : 0;
  v1 += v0; v2 += v1; v3 += v2;
  int tot = v3;
  sh[t] = tot;
  __syncthreads();
  for (int o = 1; o < 256; o <<= 1) {
    int x = (t >= o) ? sh[t - o] : 0;
    __syncthreads();
    sh[t] += x;
    __syncthreads();
  }
  int excl = sh[t] - tot;
  if (base + 0 < n) data[base + 0] = v0 + excl;
  if (base + 1 < n) data[base + 1] = v1 + excl;
  if (base + 2 < n) data[base + 2] = v2 + excl;
  if (base + 3 < n) data[base + 3] = v3 + excl;
  if (t == 255) blksum[blockIdx.x] = sh[255];
}

__global__ __launch_bounds__(256) void k_scan2(int* __restrict__ blksum, int nb) {
  __shared__ int sh[256];
  int t = threadIdx.x;
  sh[t] = (t < nb) ? blksum[t] : 0;
  __syncthreads();
  for (int o = 1; o < 256; o <<= 1) {
    int x = (t >= o) ? sh[t - o] : 0;
    __syncthreads();
    sh[t] += x;
    __syncthreads();
  }
  if (t < nb) blksum[t] = sh[t];
}

__global__ __launch_bounds__(256) void k_scan3(int* __restrict__ data, int n,
                                               const int* __restrict__ blksum) {
  int b = blockIdx.x;
  if (b == 0) return;
  int add = blksum[b - 1];
  int base = b * 1024 + threadIdx.x * 4;
  for (int j = 0; j < 4; ++j)
    if (base + j < n) data[base + j] += add;
}

__global__ __launch_bounds__(256) void k_scatter(const int* __restrict__ dst,
                                                 const int* __restrict__ src,
                                                 const int* __restrict__ off,
                                                 int* __restrict__ cursor,
                                                 int* __restrict__ srcs) {
  int e = blockIdx.x * 256 + threadIdx.x;
  if (e >= N_EDGES) return;
  int d = dst[e];
  int pos = off[d] + atomicAdd(&cursor[d], 1);
  srcs[pos] = src[e];
}

__global__ __launch_bounds__(256) void k_sortseg(const int* __restrict__ off,
                                                 int* __restrict__ srcs) {
  int n = blockIdx.x * 256 + threadIdx.x;
  if (n >= N_NODES) return;
  int beg = off[n], end = off[n + 1];
  for (int i = beg + 1; i < end; ++i) {
    int key = srcs[i];
    int j = i - 1;
    while (j >= beg && srcs[j] > key) { srcs[j + 1] = srcs[j]; --j; }
    srcs[j + 1] = key;
  }
}

// -------------------------------------------- nf fp32 [N,74] -> bf16 [N,96]
__global__ __launch_bounds__(256) void k_pad_nf(const float* __restrict__ nf,
                                                ushort* __restrict__ nfb) {
  long long idx = (long long)blockIdx.x * 256 + threadIdx.x;
  if (idx >= (long long)N_NODES * ENC_KP) return;
  int n = (int)(idx / ENC_KP);
  int c = (int)(idx - (long long)n * ENC_KP);
  ushort v = 0;
  if (c < F_IN) v = f2bf(nf[(size_t)n * F_IN + c]);
  nfb[idx] = v;
}

// ----------- prep stage 1: wv0[c][o] = sum_j W0[o][ (c&3)*64 + j ] * av[j]
// (c<4: al0 head c; c in 4..8: ar0 head c-4) -- 512 entries, 64 FMA each
__global__ __launch_bounds__(256) void k_prep_av(const float* __restrict__ W0,
                                                 const float* __restrict__ al0,
                                                 const float* __restrict__ ar0,
                                                 float* __restrict__ wv0) {
  for (int i = threadIdx.x; i < 8 * HID; i += 256) {
    int c = i >> 6, o = i & 63;
    const float* av = (c < 4) ? al0 + (c & 3) * 64 : ar0 + (c & 3) * 64;
    const float* wp = W0 + (size_t)o * HID4 + (c & 3) * 64;
    float acc = 0.f;
    for (int j = 0; j < 64; ++j) acc = fmaf(wp[j], av[j], acc);
    wv0[i] = acc;
  }
}

// ------------------------- prep stage 2 (all branches <= 64 iterations)
// Wcomb[256][96] = (We@W0)^T, bcomb[256] = be@W0,
// Wlrc[16][96] via wv0, elc[8] via wv0,
// Wt1/Wt2 [256][256] transposes, Wlr1/Wlr2 [16][256].
__global__ __launch_bounds__(256) void k_prep(
    const float* __restrict__ enc_W, const float* __restrict__ enc_b,
    const float* __restrict__ W0, const float* __restrict__ W1,
    const float* __restrict__ W2,
    const float* __restrict__ al1, const float* __restrict__ ar1,
    const float* __restrict__ al2, const float* __restrict__ ar2,
    const float* __restrict__ wv0,
    ushort* __restrict__ Wcomb, float* __restrict__ bcomb,
    ushort* __restrict__ Wlrc, float* __restrict__ elc,
    ushort* __restrict__ Wt1, ushort* __restrict__ Wt2,
    ushort* __restrict__ Wlr1, ushort* __restrict__ Wlr2) {
  const int S0 = HID4 * ENC_KP;          // Wcomb
  const int S1 = S0 + HID4;              // bcomb
  const int S2 = S1 + 16 * ENC_KP;       // Wlrc
  const int S3 = S2 + 8;                 // elc
  const int S4 = S3 + HID4 * HID4;       // Wt1
  const int S5 = S4 + HID4 * HID4;       // Wt2
  const int S6 = S5 + 16 * HID4;         // Wlr1
  const int S7 = S6 + 16 * HID4;         // Wlr2
  int idx = blockIdx.x * 256 + threadIdx.x;
  if (idx < S0) {
    int c = idx / ENC_KP, k = idx - c * ENC_KP;
    float acc = 0.f;
    if (k < F_IN) {
      const float* we = enc_W + (size_t)k * HID;
      for (int o = 0; o < HID; ++o) acc = fmaf(we[o], W0[(size_t)o * HID4 + c], acc);
    }
    Wcomb[idx] = f2bf(acc);
  } else if (idx < S1) {
    int c = idx - S0;
    float acc = 0.f;
    for (int o = 0; o < HID; ++o) acc = fmaf(enc_b[o], W0[(size_t)o * HID4 + c], acc);
    bcomb[c] = acc;
  } else if (idx < S2) {
    int i = idx - S1;
    int c = i / ENC_KP, k = i - c * ENC_KP;
    float acc = 0.f;
    if (c < 8 && k < F_IN) {
      const float* we = enc_W + (size_t)k * HID;
      const float* wv = wv0 + (size_t)c * HID;
      for (int o = 0; o < HID; ++o) acc = fmaf(we[o], wv[o], acc);
    }
    Wlrc[i] = f2bf(acc);
  } else if (idx < S3) {
    int c = idx - S2;
    float acc = 0.f;
    const float* wv = wv0 + (size_t)c * HID;
    for (int o = 0; o < HID; ++o) acc = fmaf(enc_b[o], wv[o], acc);
    elc[c] = acc;
  } else if (idx < S4) {
    int i = idx - S3; int k = i >> 8, n = i & 255;
    Wt1[(size_t)n * HID4 + k] = f2bf(W1[i]);
  } else if (idx < S5) {
    int i = idx - S4; int k = i >> 8, n = i & 255;
    Wt2[(size_t)n * HID4 + k] = f2bf(W2[i]);
  } else if (idx < S6) {
    int i = idx - S5; int c = i / HID4, k = i - c * HID4;
    float acc = 0.f;
    if (c < 8) {
      const float* av = (c < 4) ? al1 + (c & 3) * 64 : ar1 + (c & 3) * 64;
      const float* wp = W1 + (size_t)k * HID4 + (c & 3) * 64;
      for (int o = 0; o < 64; ++o) acc = fmaf(wp[o], av[o], acc);
    }
    Wlr1[i] = f2bf(acc);
  } else if (idx < S7) {
    int i = idx - S6; int c = i / HID4, k = i - c * HID4;
    float acc = 0.f;
    if (c < 8) {
      const float* av = (c < 4) ? al2 + (c & 3) * 64 : ar2 + (c & 3) * 64;
      const float* wp = W2 + (size_t)k * HID4 + (c & 3) * 64;
      for (int o = 0; o < 64; ++o) acc = fmaf(wp[o], av[o], acc);
    }
    Wlr2[i] = f2bf(acc);
  }
}

// ---------------------------------------------------------- bf16 MFMA GEMM
// 128x128 tile, 4 waves, dbuf LDS via global_load_lds, XCD-pairing 1D grid.
// el/er fused as MFMA columns (no shuffle epilogue). BIAS variant adds
// bcomb[col] to C and elc[cc] to el/er (fused encoder+layer0 path).
template <int K, bool BIAS>
__global__ __launch_bounds__(256) void k_gemm_mfma(const ushort* __restrict__ A,
                                                   const ushort* __restrict__ Bt,
                                                   const ushort* __restrict__ Wlr,
                                                   const float* __restrict__ bcomb,
                                                   const float* __restrict__ elc,
                                                   ushort* __restrict__ Cb,
                                                   float* __restrict__ el,
                                                   float* __restrict__ er,
                                                   int n_rows) {
  __shared__ __align__(16) ushort As[2][128 * 32];
  __shared__ __align__(16) ushort Bs[2][128 * 32];
  int bid = blockIdx.x;
  int rpan = (bid >> 4) * 8 + (bid & 7);
  int nrp = (n_rows + 127) / 128;
  if (rpan >= nrp) return;
  int brow = rpan * 128;
  int bcol = ((bid >> 3) & 1) * 128;

  int t = threadIdx.x;
  int lane = t & 63;
  int wid = t >> 6;
  int wr = wid >> 1, wc = wid & 1;

  f32x4 acc[4][4];
#pragma unroll
  for (int m = 0; m < 4; ++m)
#pragma unroll
    for (int n = 0; n < 4; ++n) acc[m][n] = (f32x4)(0.f);

  int srow0 = (wid * 2 + 0) * 16 + (lane >> 2);
  int srow1 = (wid * 2 + 1) * 16 + (lane >> 2);
  int skc = (lane & 3) * 8;
  int ga0 = brow + srow0; if (ga0 > n_rows - 1) ga0 = n_rows - 1;
  int ga1 = brow + srow1; if (ga1 > n_rows - 1) ga1 = n_rows - 1;
  const ushort* pa0 = A + (size_t)ga0 * K + skc;
  const ushort* pa1 = A + (size_t)ga1 * K + skc;
  const ushort* pb0 = Bt + (size_t)(bcol + srow0) * K + skc;
  const ushort* pb1 = Bt + (size_t)(bcol + srow1) * K + skc;
  int lo0 = (wid * 2 + 0) * 512;
  int lo1 = (wid * 2 + 1) * 512;

  int fr = lane & 15;
  int ko = (lane >> 4) * 8;

  bool do_lr = (bcol == 0) && (wc == 0);
  short8 blrr[K / 32];
  f32x4 acc_lr[4];
#pragma unroll
  for (int m = 0; m < 4; ++m) acc_lr[m] = (f32x4)(0.f);
  if (do_lr) {
#pragma unroll
    for (int ks = 0; ks < K / 32; ++ks)
      blrr[ks] = *(const short8*)(Wlr + (size_t)fr * K + ks * 32 + ko);
  }

  glds16(pa0, &As[0][lo0]);
  glds16(pa1, &As[0][lo1]);
  glds16(pb0, &Bs[0][lo0]);
  glds16(pb1, &Bs[0][lo1]);
  __syncthreads();

#pragma unroll
  for (int kstep = 0; kstep < K / 32; ++kstep) {
    int k0 = kstep * 32;
    int cur = kstep & 1;
    if (k0 + 32 < K) {
      glds16(pa0 + k0 + 32, &As[cur ^ 1][lo0]);
      glds16(pa1 + k0 + 32, &As[cur ^ 1][lo1]);
      glds16(pb0 + k0 + 32, &Bs[cur ^ 1][lo0]);
      glds16(pb1 + k0 + 32, &Bs[cur ^ 1][lo1]);
    }
    short8 a[4], b[4];
#pragma unroll
    for (int m = 0; m < 4; ++m)
      a[m] = *(const short8*)(&As[cur][0] + (wr * 64 + m * 16 + fr) * 32 + ko);
#pragma unroll
    for (int n = 0; n < 4; ++n)
      b[n] = *(const short8*)(&Bs[cur][0] + (wc * 64 + n * 16 + fr) * 32 + ko);
#pragma unroll
    for (int m = 0; m < 4; ++m)
#pragma unroll
      for (int n = 0; n < 4; ++n)
        acc[m][n] = __builtin_amdgcn_mfma_f32_16x16x32_bf16(a[m], b[n], acc[m][n], 0, 0, 0);
    if (do_lr) {
#pragma unroll
      for (int m = 0; m < 4; ++m)
        acc_lr[m] = __builtin_amdgcn_mfma_f32_16x16x32_bf16(a[m], blrr[kstep], acc_lr[m], 0, 0, 0);
    }
    __syncthreads();
  }

  int r0 = (lane >> 4) * 4;
  int cc = lane & 15;
  float bc[4];
  if constexpr (BIAS) {
#pragma unroll
    for (int n = 0; n < 4; ++n) bc[n] = bcomb[bcol + wc * 64 + n * 16 + cc];
  }
#pragma unroll
  for (int m = 0; m < 4; ++m) {
#pragma unroll
    for (int j = 0; j < 4; ++j) {
      int row = brow + wr * 64 + m * 16 + r0 + j;
      if (row >= n_rows) continue;
#pragma unroll
      for (int n = 0; n < 4; ++n) {
        float v = acc[m][n][j];
        if constexpr (BIAS) v += bc[n];
        Cb[(size_t)row * HID4 + bcol + wc * 64 + n * 16 + cc] = f2bf(v);
      }
    }
  }
  if (do_lr && cc < 8) {
    float ec = 0.f;
    if constexpr (BIAS) ec = elc[cc];
#pragma unroll
    for (int m = 0; m < 4; ++m)
#pragma unroll
      for (int j = 0; j < 4; ++j) {
        int row = brow + wr * 64 + m * 16 + r0 + j;
        if (row >= n_rows) continue;
        float v = acc_lr[m][j] + ec;
        if (cc < 4) el[(size_t)row * NHEAD + cc] = v;
        else er[(size_t)row * NHEAD + (cc - 4)] = v;
      }
  }
}

// ---------- shift-free softmax aggregate: 4 nodes/wave, 16 lanes per node
__global__ __launch_bounds__(256) void k_agg(const ushort* __restrict__ zb,
                                             const float* __restrict__ el,
                                             const float* __restrict__ er,
                                             const int* __restrict__ off,
                                             const int* __restrict__ srcs,
                                             const float* __restrict__ bias,
                                             ushort* __restrict__ outb) {
  int w = (blockIdx.x * 256 + threadIdx.x) >> 6;
  int lane = threadIdx.x & 63;
  int n = w * 4 + (lane >> 4);
  int li = lane & 15;
  if (n >= N_NODES) return;
  int h = li >> 2;   // head (4 lanes per head)
  int c = li * 16;   // feature base, 16 bf16 per lane
  int beg = off[n], end = off[n + 1];
  float erh = er[(size_t)n * NHEAD + h];

  float s = 0.f;
  float acc[16];
#pragma unroll
  for (int j = 0; j < 16; ++j) acc[j] = 0.f;

  float e0 = 0.f, e1 = 0.f, e2 = 0.f;
  int4 za0 = make_int4(0, 0, 0, 0), zb0 = za0;
  int4 za1 = za0, zb1 = za0, za2 = za0, zb2 = za0;
  if (beg < end) {
    int sn = srcs[beg];
    e0 = el[(size_t)sn * NHEAD + h];
    const ushort* zp = zb + (size_t)sn * HID4 + c;
    za0 = *(const int4*)zp; zb0 = *(const int4*)(zp + 8);
  }
  if (beg + 1 < end) {
    int sn = srcs[beg + 1];
    e1 = el[(size_t)sn * NHEAD + h];
    const ushort* zp = zb + (size_t)sn * HID4 + c;
    za1 = *(const int4*)zp; zb1 = *(const int4*)(zp + 8);
  }
  if (beg + 2 < end) {
    int sn = srcs[beg + 2];
    e2 = el[(size_t)sn * NHEAD + h];
    const ushort* zp = zb + (size_t)sn * HID4 + c;
    za2 = *(const int4*)zp; zb2 = *(const int4*)(zp + 8);
  }

  for (int p = beg; p < end; ++p) {
    float ev = e0;
    int4 va = za0, vb = zb0;
    e0 = e1; za0 = za1; zb0 = zb1;
    e1 = e2; za1 = za2; zb1 = zb2;
    if (p + 3 < end) {
      int sn = srcs[p + 3];
      e2 = el[(size_t)sn * NHEAD + h];
      const ushort* zp = zb + (size_t)sn * HID4 + c;
      za2 = *(const int4*)zp; zb2 = *(const int4*)(zp + 8);
    }
    float pv = __expf(leaky(ev + erh));
    s += pv;
    const ushort* ua = (const ushort*)&va;
    const ushort* ub = (const ushort*)&vb;
#pragma unroll
    for (int j = 0; j < 8; ++j) acc[j] = fmaf(pv, bf2f(ua[j]), acc[j]);
#pragma unroll
    for (int j = 0; j < 8; ++j) acc[8 + j] = fmaf(pv, bf2f(ub[j]), acc[8 + j]);
  }
  float inv = (s > 0.f) ? 1.f / s : 0.f;
  float bb[16];
#pragma unroll
  for (int j = 0; j < 16; j += 4) {
    float4 b4 = *(const float4*)(bias + c + j);
    bb[j] = b4.x; bb[j + 1] = b4.y; bb[j + 2] = b4.z; bb[j + 3] = b4.w;
  }
  int4 ov0, ov1;
  ushort* os0 = (ushort*)&ov0;
  ushort* os1 = (ushort*)&ov1;
#pragma unroll
  for (int j = 0; j < 8; ++j) os0[j] = f2bf(fmaxf(acc[j] * inv + bb[j], 0.f));
#pragma unroll
  for (int j = 0; j < 8; ++j) os1[j] = f2bf(fmaxf(acc[8 + j] * inv + bb[8 + j], 0.f));
  ushort* op = outb + (size_t)n * HID4 + c;
  *(int4*)op = ov0;
  *(int4*)(op + 8) = ov1;
}

// ---------------------------------------------------------------- readout
__global__ __launch_bounds__(256) void k_pool_mlp(const ushort* __restrict__ h,
                                                  const float* __restrict__ r1W,
                                                  const float* __restrict__ r1b,
                                                  const float* __restrict__ r2W,
                                                  const float* __restrict__ r2b,
                                                  float* __restrict__ out) {
  __shared__ float pooled[3 * HID4];
  __shared__ float part[4][HID];
  __shared__ float mid[HID];
  int g = blockIdx.x;
  int t = threadIdx.x;
  const ushort* base = h + (size_t)g * NODES_PER_G * HID4;
  float sum = 0.f, mx = -1e30f;
  for (int i = 0; i < NODES_PER_G; ++i) {
    float v = bf2f(base[(size_t)i * HID4 + t]);
    sum += v;
    mx = fmaxf(mx, v);
  }
  pooled[t] = sum / (float)NODES_PER_G;
  pooled[HID4 + t] = mx;
  pooled[2 * HID4 + t] = sum;
  __syncthreads();
  {
    int o = t & 63, chunk = t >> 6;
    float acc = 0.f;
    int k0 = chunk * 192;
    for (int k = k0; k < k0 + 192; ++k) acc = fmaf(pooled[k], r1W[k * HID + o], acc);
    part[chunk][o] = acc;
  }
  __syncthreads();
  if (t < HID) {
    float acc = r1b[t] + part[0][t] + part[1][t] + part[2][t] + part[3][t];
    mid[t] = fmaxf(acc, 0.f);
  }
  __syncthreads();
  if (t < OUT_DIM) {
    float acc = r2b[t];
    for (int k = 0; k < HID; ++k) acc = fmaf(mid[k], r2W[k * OUT_DIM + t], acc);
    out[(size_t)g * OUT_DIM + t] = acc;
  }
}

// ---------------------------------------------------------------- launch
extern "C" void kernel_launch(void* const* d_in, const int* in_sizes, int n_in,
                              void* d_out, int out_size, void* d_ws, size_t ws_size,
                              hipStream_t stream) {
  const float* node_feat = (const float*)d_in[0];
  const int* src = (const int*)d_in[1];
  const int* dst = (const int*)d_in[2];
  const float* enc_W = (const float*)d_in[4];
  const float* enc_b = (const float*)d_in[5];
  const float* Wl[3] = {(const float*)d_in[6], (const float*)d_in[10], (const float*)d_in[14]};
  const float* all_[3] = {(const float*)d_in[7], (const float*)d_in[11], (const float*)d_in[15]};
  const float* arl[3] = {(const float*)d_in[8], (const float*)d_in[12], (const float*)d_in[16]};
  const float* bl[3] = {(const float*)d_in[9], (const float*)d_in[13], (const float*)d_in[17]};
  const float* r1W = (const float*)d_in[18];
  const float* r1b = (const float*)d_in[19];
  const float* r2W = (const float*)d_in[20];
  const float* r2b = (const float*)d_in[21];
  float* out = (float*)d_out;

  char* p = (char*)d_ws;
  auto alloc = [&](size_t bytes) {
    void* r = (void*)p;
    p += (bytes + 255) & ~(size_t)255;
    return r;
  };
  int* off = (int*)alloc((N_NODES + 1) * sizeof(int));
  int* cursor = (int*)alloc(N_NODES * sizeof(int));
  int* srcs = (int*)alloc(N_EDGES * sizeof(int));
  int* blksum = (int*)alloc(256 * sizeof(int));
  float* el = (float*)alloc((size_t)N_NODES * NHEAD * sizeof(float));
  float* er = (float*)alloc((size_t)N_NODES * NHEAD * sizeof(float));
  ushort* Qb = (ushort*)alloc((size_t)N_NODES * HID4 * sizeof(ushort));
  ushort* Pb = (ushort*)alloc((size_t)N_NODES * HID4 * sizeof(ushort));
  ushort* nfb = (ushort*)alloc((size_t)N_NODES * ENC_KP * sizeof(ushort));
  float* wv0 = (float*)alloc((size_t)8 * HID * sizeof(float));
  ushort* Wcomb = (ushort*)alloc((size_t)HID4 * ENC_KP * sizeof(ushort));
  float* bcomb = (float*)alloc((size_t)HID4 * sizeof(float));
  ushort* Wlrc = (ushort*)alloc((size_t)16 * ENC_KP * sizeof(ushort));
  float* elc = (float*)alloc(8 * sizeof(float));
  ushort* Wt1 = (ushort*)alloc((size_t)HID4 * HID4 * sizeof(ushort));
  ushort* Wt2 = (ushort*)alloc((size_t)HID4 * HID4 * sizeof(ushort));
  ushort* Wlr1 = (ushort*)alloc((size_t)16 * HID4 * sizeof(ushort));
  ushort* Wlr2 = (ushort*)alloc((size_t)16 * HID4 * sizeof(ushort));

  // ---- CSR build (deterministic via per-segment value sort)
  hipMemsetAsync(off, 0, (N_NODES + 1) * sizeof(int), stream);
  hipMemsetAsync(cursor, 0, N_NODES * sizeof(int), stream);
  k_count<<<(N_EDGES + 255) / 256, 256, 0, stream>>>(dst, off);
  const int SCAN_N = N_NODES + 1;
  const int NB = (SCAN_N + 1023) / 1024;
  k_scan1<<<NB, 256, 0, stream>>>(off, SCAN_N, blksum);
  k_scan2<<<1, 256, 0, stream>>>(blksum, NB);
  k_scan3<<<NB, 256, 0, stream>>>(off, SCAN_N, blksum);
  k_scatter<<<(N_EDGES + 255) / 256, 256, 0, stream>>>(dst, src, off, cursor, srcs);
  k_sortseg<<<(N_NODES + 255) / 256, 256, 0, stream>>>(off, srcs);

  // ---- weight prep (two tiny launches) + nf pad/convert
  k_prep_av<<<1, 256, 0, stream>>>(Wl[0], all_[0], arl[0], wv0);
  const int PREP_N = HID4 * ENC_KP + HID4 + 16 * ENC_KP + 8 +
                     2 * HID4 * HID4 + 2 * 16 * HID4;
  k_prep<<<(PREP_N + 255) / 256, 256, 0, stream>>>(
      enc_W, enc_b, Wl[0], Wl[1], Wl[2],
      all_[1], arl[1], all_[2], arl[2], wv0,
      Wcomb, bcomb, Wlrc, elc, Wt1, Wt2, Wlr1, Wlr2);
  k_pad_nf<<<(int)(((long long)N_NODES * ENC_KP + 255) / 256), 256, 0, stream>>>(node_feat, nfb);

  // ---- fused encoder+layer0 GEMM (K=96, dbuf glds16) -> Qb, el, er ; agg
  const int NRP = (N_NODES + 127) / 128;
  const int GEMM_BLOCKS = ((NRP + 7) / 8) * 16;
  const int AGG_BLOCKS = ((N_NODES + 3) / 4 + 3) / 4;
  k_gemm_mfma<ENC_KP, true><<<GEMM_BLOCKS, 256, 0, stream>>>(
      nfb, Wcomb, Wlrc, bcomb, elc, Qb, el, er, N_NODES);
  k_agg<<<AGG_BLOCKS, 256, 0, stream>>>(Qb, el, er, off, srcs, bl[0], Pb);

  // ---- layers 1,2: GEMM (+el/er via MFMA) ; agg
  const ushort* Wts[2] = {Wt1, Wt2};
  const ushort* Wlrs[2] = {Wlr1, Wlr2};
  for (int l = 0; l < 2; ++l) {
    k_gemm_mfma<HID4, false><<<GEMM_BLOCKS, 256, 0, stream>>>(
        Pb, Wts[l], Wlrs[l], nullptr, nullptr, Qb, el, er, N_NODES);
    k_agg<<<AGG_BLOCKS, 256, 0, stream>>>(Qb, el, er, off, srcs, bl[l + 1], Pb);
  }

  // ---- readout
  k_pool_mlp<<<N_GRAPHS, 256, 0, stream>>>(Pb, r1W, r1b, r2W, r2b, out);
}

// Round 18
// 352.811 us; speedup vs baseline: 1.3101x; 1.0361x over previous
//
#include <hip/hip_runtime.h>

#define N_NODES 100000
#define N_EDGES 400000
#define N_GRAPHS 2000
#define F_IN 74
#define ENC_KP 96
#define HID 64
#define NHEAD 4
#define HID4 256
#define OUT_DIM 128
#define NODES_PER_G 50

typedef __attribute__((ext_vector_type(8))) short short8;
typedef __attribute__((ext_vector_type(4))) float f32x4;

__device__ inline ushort f2bf(float f) {
  union { float f; unsigned u; } v; v.f = f;
  unsigned u = v.u;
  return (ushort)((u + 0x7FFFu + ((u >> 16) & 1u)) >> 16);
}
__device__ inline float bf2f(ushort b) {
  union { unsigned u; float f; } v; v.u = ((unsigned)b) << 16;
  return v.f;
}
__device__ inline float leaky(float x) { return x >= 0.f ? x : 0.2f * x; }

// async global->LDS, 16B per lane, dest = uniform base + lane*16
__device__ inline void glds16(const ushort* g, ushort* l) {
  __builtin_amdgcn_global_load_lds(
      (const __attribute__((address_space(1))) void*)g,
      (__attribute__((address_space(3))) void*)l, 16, 0, 0);
}

// ---------------------------------------------------------------- CSR build
__global__ __launch_bounds__(256) void k_count(const int* __restrict__ dst,
                                               int* __restrict__ off) {
  int e = blockIdx.x * 256 + threadIdx.x;
  if (e < N_EDGES) atomicAdd(&off[dst[e] + 1], 1);
}

__global__ __launch_bounds__(256) void k_scan1(int* __restrict__ data, int n,
                                               int* __restrict__ blksum) {
  __shared__ int sh[256];
  int t = threadIdx.x;
  int base = blockIdx.x * 1024 + t * 4;
  int v0 = (base + 0 < n) ? data[base + 0] : 0;
  int v1 = (base + 1 < n) ? data[base + 1] : 0;
  int v2 = (base + 2 < n) ? data[base + 2] : 0;
  int v3 = (base + 3 < n) ? data[base + 3] : 0;
  v1 += v0; v2 += v1; v3 += v2;
  int tot = v3;
  sh[t] = tot;
  __syncthreads();
  for (int o = 1; o < 256; o <<= 1) {
    int x = (t >= o) ? sh[t - o] : 0;
    __syncthreads();
    sh[t] += x;
    __syncthreads();
  }
  int excl = sh[t] - tot;
  if (base + 0 < n) data[base + 0] = v0 + excl;
  if (base + 1 < n) data[base + 1] = v1 + excl;
  if (base + 2 < n) data[base + 2] = v2 + excl;
  if (base + 3 < n) data[base + 3] = v3 + excl;
  if (t == 255) blksum[blockIdx.x] = sh[255];
}

__global__ __launch_bounds__(256) void k_scan2(int* __restrict__ blksum, int nb) {
  __shared__ int sh[256];
  int t = threadIdx.x;
  sh[t] = (t < nb) ? blksum[t] : 0;
  __syncthreads();
  for (int o = 1; o < 256; o <<= 1) {
    int x = (t >= o) ? sh[t - o] : 0;
    __syncthreads();
    sh[t] += x;
    __syncthreads();
  }
  if (t < nb) blksum[t] = sh[t];
}

__global__ __launch_bounds__(256) void k_scan3(int* __restrict__ data, int n,
                                               const int* __restrict__ blksum) {
  int b = blockIdx.x;
  if (b == 0) return;
  int add = blksum[b - 1];
  int base = b * 1024 + threadIdx.x * 4;
  for (int j = 0; j < 4; ++j)
    if (base + j < n) data[base + j] += add;
}

__global__ __launch_bounds__(256) void k_scatter(const int* __restrict__ dst,
                                                 const int* __restrict__ src,
                                                 const int* __restrict__ off,
                                                 int* __restrict__ cursor,
                                                 int* __restrict__ srcs) {
  int e = blockIdx.x * 256 + threadIdx.x;
  if (e >= N_EDGES) return;
  int d = dst[e];
  int pos = off[d] + atomicAdd(&cursor[d], 1);
  srcs[pos] = src[e];
}

__global__ __launch_bounds__(256) void k_sortseg(const int* __restrict__ off,
                                                 int* __restrict__ srcs) {
  int n = blockIdx.x * 256 + threadIdx.x;
  if (n >= N_NODES) return;
  int beg = off[n], end = off[n + 1];
  for (int i = beg + 1; i < end; ++i) {
    int key = srcs[i];
    int j = i - 1;
    while (j >= beg && srcs[j] > key) { srcs[j + 1] = srcs[j]; --j; }
    srcs[j + 1] = key;
  }
}

// ------------------------- consolidated weight prep (one launch, upfront)
// Wte [64][96]; Wt_l [256][K_l]; Wlr_l [16][K_l] (el/er as GEMM columns)
__global__ __launch_bounds__(256) void k_prep(
    const float* __restrict__ enc_W,
    const float* __restrict__ W0, const float* __restrict__ W1,
    const float* __restrict__ W2,
    const float* __restrict__ al0, const float* __restrict__ ar0,
    const float* __restrict__ al1, const float* __restrict__ ar1,
    const float* __restrict__ al2, const float* __restrict__ ar2,
    ushort* __restrict__ Wte,
    ushort* __restrict__ Wt0, ushort* __restrict__ Wt1,
    ushort* __restrict__ Wt2,
    ushort* __restrict__ Wlr0, ushort* __restrict__ Wlr1,
    ushort* __restrict__ Wlr2) {
  const int S0 = HID * ENC_KP;
  const int S1 = S0 + HID * HID4;
  const int S2 = S1 + HID4 * HID4;
  const int S3 = S2 + HID4 * HID4;
  const int S4 = S3 + 16 * HID;
  const int S5 = S4 + 16 * HID4;
  const int S6 = S5 + 16 * HID4;
  int idx = blockIdx.x * 256 + threadIdx.x;
  if (idx < S0) {
    int col = idx / ENC_KP, k = idx - col * ENC_KP;
    Wte[idx] = (k < F_IN) ? f2bf(enc_W[(size_t)k * HID + col]) : (ushort)0;
  } else if (idx < S1) {
    int i = idx - S0; int k = i >> 8, n = i & 255;
    Wt0[(size_t)n * HID + k] = f2bf(W0[i]);
  } else if (idx < S2) {
    int i = idx - S1; int k = i >> 8, n = i & 255;
    Wt1[(size_t)n * HID4 + k] = f2bf(W1[i]);
  } else if (idx < S3) {
    int i = idx - S2; int k = i >> 8, n = i & 255;
    Wt2[(size_t)n * HID4 + k] = f2bf(W2[i]);
  } else if (idx < S4) {
    int i = idx - S3; int c = i / HID, k = i - c * HID;
    float acc = 0.f;
    if (c < 8) {
      const float* av = (c < 4) ? al0 + (c & 3) * 64 : ar0 + (c & 3) * 64;
      const float* wp = W0 + (size_t)k * HID4 + (c & 3) * 64;
      for (int o = 0; o < 64; ++o) acc = fmaf(wp[o], av[o], acc);
    }
    Wlr0[(size_t)c * HID + k] = f2bf(acc);
  } else if (idx < S5) {
    int i = idx - S4; int c = i / HID4, k = i - c * HID4;
    float acc = 0.f;
    if (c < 8) {
      const float* av = (c < 4) ? al1 + (c & 3) * 64 : ar1 + (c & 3) * 64;
      const float* wp = W1 + (size_t)k * HID4 + (c & 3) * 64;
      for (int o = 0; o < 64; ++o) acc = fmaf(wp[o], av[o], acc);
    }
    Wlr1[(size_t)c * HID4 + k] = f2bf(acc);
  } else if (idx < S6) {
    int i = idx - S5; int c = i / HID4, k = i - c * HID4;
    float acc = 0.f;
    if (c < 8) {
      const float* av = (c < 4) ? al2 + (c & 3) * 64 : ar2 + (c & 3) * 64;
      const float* wp = W2 + (size_t)k * HID4 + (c & 3) * 64;
      for (int o = 0; o < 64; ++o) acc = fmaf(wp[o], av[o], acc);
    }
    Wlr2[(size_t)c * HID4 + k] = f2bf(acc);
  }
}

// ------------------------------------------------------ encoder MFMA GEMM
__global__ __launch_bounds__(256) void k_enc_mfma(const float* __restrict__ nf,
                                                  const ushort* __restrict__ Bt,
                                                  const float* __restrict__ bias,
                                                  ushort* __restrict__ Cb) {
  __shared__ ushort As[128][104];
  __shared__ ushort Bs[64][104];
  int t = threadIdx.x;
  int lane = t & 63;
  int wid = t >> 6;
  int brow = blockIdx.x * 128;

  for (int i = t; i < 128 * ENC_KP; i += 256) {
    int r = i / ENC_KP;
    int c = i - r * ENC_KP;
    int gr = brow + r;
    float v = 0.f;
    if (gr < N_NODES && c < F_IN) v = nf[(size_t)gr * F_IN + c];
    As[r][c] = f2bf(v);
  }
  if (t < 128) {
    int r = t >> 1;
    int o = (t & 1) * 48;
#pragma unroll
    for (int i = 0; i < 6; ++i)
      *(int4*)&Bs[r][o + i * 8] = *(const int4*)(Bt + (size_t)r * ENC_KP + o + i * 8);
  }
  __syncthreads();

  int fr = lane & 15;
  int ko = (lane >> 4) * 8;
  f32x4 acc[2][4];
#pragma unroll
  for (int m = 0; m < 2; ++m)
#pragma unroll
    for (int n = 0; n < 4; ++n) acc[m][n] = (f32x4)(0.f);

#pragma unroll
  for (int ks = 0; ks < 3; ++ks) {
    short8 a[2], b[4];
#pragma unroll
    for (int m = 0; m < 2; ++m) a[m] = *(const short8*)&As[wid * 32 + m * 16 + fr][ks * 32 + ko];
#pragma unroll
    for (int n = 0; n < 4; ++n) b[n] = *(const short8*)&Bs[n * 16 + fr][ks * 32 + ko];
#pragma unroll
    for (int m = 0; m < 2; ++m)
#pragma unroll
      for (int n = 0; n < 4; ++n)
        acc[m][n] = __builtin_amdgcn_mfma_f32_16x16x32_bf16(a[m], b[n], acc[m][n], 0, 0, 0);
  }

  int r0 = (lane >> 4) * 4;
  int cc = lane & 15;
#pragma unroll
  for (int m = 0; m < 2; ++m) {
#pragma unroll
    for (int j = 0; j < 4; ++j) {
      int row = brow + wid * 32 + m * 16 + r0 + j;
      if (row >= N_NODES) continue;
#pragma unroll
      for (int n = 0; n < 4; ++n) {
        int col = n * 16 + cc;
        Cb[(size_t)row * HID + col] = f2bf(acc[m][n][j] + bias[col]);
      }
    }
  }
}

// ---------------------------------------------------------- bf16 MFMA GEMM
// 128x128 tile, 4 waves, dbuf LDS via global_load_lds, XCD-pairing 1D grid.
// el/er fused as MFMA columns (no shuffle epilogue).
template <int K>
__global__ __launch_bounds__(256) void k_gemm_mfma(const ushort* __restrict__ A,
                                                   const ushort* __restrict__ Bt,
                                                   const ushort* __restrict__ Wlr,
                                                   ushort* __restrict__ Cb,
                                                   float* __restrict__ el,
                                                   float* __restrict__ er,
                                                   int n_rows) {
  __shared__ __align__(16) ushort As[2][128 * 32];
  __shared__ __align__(16) ushort Bs[2][128 * 32];
  int bid = blockIdx.x;
  int rpan = (bid >> 4) * 8 + (bid & 7);
  int nrp = (n_rows + 127) / 128;
  if (rpan >= nrp) return;
  int brow = rpan * 128;
  int bcol = ((bid >> 3) & 1) * 128;

  int t = threadIdx.x;
  int lane = t & 63;
  int wid = t >> 6;
  int wr = wid >> 1, wc = wid & 1;

  f32x4 acc[4][4];
#pragma unroll
  for (int m = 0; m < 4; ++m)
#pragma unroll
    for (int n = 0; n < 4; ++n) acc[m][n] = (f32x4)(0.f);

  int srow0 = (wid * 2 + 0) * 16 + (lane >> 2);
  int srow1 = (wid * 2 + 1) * 16 + (lane >> 2);
  int skc = (lane & 3) * 8;
  int ga0 = brow + srow0; if (ga0 > n_rows - 1) ga0 = n_rows - 1;
  int ga1 = brow + srow1; if (ga1 > n_rows - 1) ga1 = n_rows - 1;
  const ushort* pa0 = A + (size_t)ga0 * K + skc;
  const ushort* pa1 = A + (size_t)ga1 * K + skc;
  const ushort* pb0 = Bt + (size_t)(bcol + srow0) * K + skc;
  const ushort* pb1 = Bt + (size_t)(bcol + srow1) * K + skc;
  int lo0 = (wid * 2 + 0) * 512;
  int lo1 = (wid * 2 + 1) * 512;

  int fr = lane & 15;
  int ko = (lane >> 4) * 8;

  bool do_lr = (bcol == 0) && (wc == 0);
  short8 blrr[K / 32];
  f32x4 acc_lr[4];
#pragma unroll
  for (int m = 0; m < 4; ++m) acc_lr[m] = (f32x4)(0.f);
  if (do_lr) {
#pragma unroll
    for (int ks = 0; ks < K / 32; ++ks)
      blrr[ks] = *(const short8*)(Wlr + (size_t)fr * K + ks * 32 + ko);
  }

  glds16(pa0, &As[0][lo0]);
  glds16(pa1, &As[0][lo1]);
  glds16(pb0, &Bs[0][lo0]);
  glds16(pb1, &Bs[0][lo1]);
  __syncthreads();

#pragma unroll
  for (int kstep = 0; kstep < K / 32; ++kstep) {
    int k0 = kstep * 32;
    int cur = kstep & 1;
    if (k0 + 32 < K) {
      glds16(pa0 + k0 + 32, &As[cur ^ 1][lo0]);
      glds16(pa1 + k0 + 32, &As[cur ^ 1][lo1]);
      glds16(pb0 + k0 + 32, &Bs[cur ^ 1][lo0]);
      glds16(pb1 + k0 + 32, &Bs[cur ^ 1][lo1]);
    }
    short8 a[4], b[4];
#pragma unroll
    for (int m = 0; m < 4; ++m)
      a[m] = *(const short8*)(&As[cur][0] + (wr * 64 + m * 16 + fr) * 32 + ko);
#pragma unroll
    for (int n = 0; n < 4; ++n)
      b[n] = *(const short8*)(&Bs[cur][0] + (wc * 64 + n * 16 + fr) * 32 + ko);
#pragma unroll
    for (int m = 0; m < 4; ++m)
#pragma unroll
      for (int n = 0; n < 4; ++n)
        acc[m][n] = __builtin_amdgcn_mfma_f32_16x16x32_bf16(a[m], b[n], acc[m][n], 0, 0, 0);
    if (do_lr) {
#pragma unroll
      for (int m = 0; m < 4; ++m)
        acc_lr[m] = __builtin_amdgcn_mfma_f32_16x16x32_bf16(a[m], blrr[kstep], acc_lr[m], 0, 0, 0);
    }
    __syncthreads();
  }

  int r0 = (lane >> 4) * 4;
  int cc = lane & 15;
#pragma unroll
  for (int m = 0; m < 4; ++m) {
#pragma unroll
    for (int j = 0; j < 4; ++j) {
      int row = brow + wr * 64 + m * 16 + r0 + j;
      if (row >= n_rows) continue;
#pragma unroll
      for (int n = 0; n < 4; ++n)
        Cb[(size_t)row * HID4 + bcol + wc * 64 + n * 16 + cc] = f2bf(acc[m][n][j]);
    }
  }
  if (do_lr && cc < 8) {
#pragma unroll
    for (int m = 0; m < 4; ++m)
#pragma unroll
      for (int j = 0; j < 4; ++j) {
        int row = brow + wr * 64 + m * 16 + r0 + j;
        if (row >= n_rows) continue;
        float v = acc_lr[m][j];
        if (cc < 4) el[(size_t)row * NHEAD + cc] = v;
        else er[(size_t)row * NHEAD + (cc - 4)] = v;
      }
  }
}

// ---------- shift-free softmax aggregate: 4 nodes/wave, 16 lanes per node
__global__ __launch_bounds__(256) void k_agg(const ushort* __restrict__ zb,
                                             const float* __restrict__ el,
                                             const float* __restrict__ er,
                                             const int* __restrict__ off,
                                             const int* __restrict__ srcs,
                                             const float* __restrict__ bias,
                                             ushort* __restrict__ outb) {
  int w = (blockIdx.x * 256 + threadIdx.x) >> 6;
  int lane = threadIdx.x & 63;
  int n = w * 4 + (lane >> 4);
  int li = lane & 15;
  if (n >= N_NODES) return;
  int h = li >> 2;
  int c = li * 16;
  int beg = off[n], end = off[n + 1];
  float erh = er[(size_t)n * NHEAD + h];

  float s = 0.f;
  float acc[16];
#pragma unroll
  for (int j = 0; j < 16; ++j) acc[j] = 0.f;

  float e0 = 0.f, e1 = 0.f, e2 = 0.f;
  int4 za0 = make_int4(0, 0, 0, 0), zb0 = za0;
  int4 za1 = za0, zb1 = za0, za2 = za0, zb2 = za0;
  if (beg < end) {
    int sn = srcs[beg];
    e0 = el[(size_t)sn * NHEAD + h];
    const ushort* zp = zb + (size_t)sn * HID4 + c;
    za0 = *(const int4*)zp; zb0 = *(const int4*)(zp + 8);
  }
  if (beg + 1 < end) {
    int sn = srcs[beg + 1];
    e1 = el[(size_t)sn * NHEAD + h];
    const ushort* zp = zb + (size_t)sn * HID4 + c;
    za1 = *(const int4*)zp; zb1 = *(const int4*)(zp + 8);
  }
  if (beg + 2 < end) {
    int sn = srcs[beg + 2];
    e2 = el[(size_t)sn * NHEAD + h];
    const ushort* zp = zb + (size_t)sn * HID4 + c;
    za2 = *(const int4*)zp; zb2 = *(const int4*)(zp + 8);
  }

  for (int p = beg; p < end; ++p) {
    float ev = e0;
    int4 va = za0, vb = zb0;
    e0 = e1; za0 = za1; zb0 = zb1;
    e1 = e2; za1 = za2; zb1 = zb2;
    if (p + 3 < end) {
      int sn = srcs[p + 3];
      e2 = el[(size_t)sn * NHEAD + h];
      const ushort* zp = zb + (size_t)sn * HID4 + c;
      za2 = *(const int4*)zp; zb2 = *(const int4*)(zp + 8);
    }
    float pv = __expf(leaky(ev + erh));
    s += pv;
    const ushort* ua = (const ushort*)&va;
    const ushort* ub = (const ushort*)&vb;
#pragma unroll
    for (int j = 0; j < 8; ++j) acc[j] = fmaf(pv, bf2f(ua[j]), acc[j]);
#pragma unroll
    for (int j = 0; j < 8; ++j) acc[8 + j] = fmaf(pv, bf2f(ub[j]), acc[8 + j]);
  }
  float inv = (s > 0.f) ? 1.f / s : 0.f;
  float bb[16];
#pragma unroll
  for (int j = 0; j < 16; j += 4) {
    float4 b4 = *(const float4*)(bias + c + j);
    bb[j] = b4.x; bb[j + 1] = b4.y; bb[j + 2] = b4.z; bb[j + 3] = b4.w;
  }
  int4 ov0, ov1;
  ushort* os0 = (ushort*)&ov0;
  ushort* os1 = (ushort*)&ov1;
#pragma unroll
  for (int j = 0; j < 8; ++j) os0[j] = f2bf(fmaxf(acc[j] * inv + bb[j], 0.f));
#pragma unroll
  for (int j = 0; j < 8; ++j) os1[j] = f2bf(fmaxf(acc[8 + j] * inv + bb[8 + j], 0.f));
  ushort* op = outb + (size_t)n * HID4 + c;
  *(int4*)op = ov0;
  *(int4*)(op + 8) = ov1;
}

// -------- layer-2 fused: aggregate + multi-pool + MLP readout (per graph)
// 4 waves x 4 node-groups x 4 iterations = 64 slots >= 50 nodes/graph.
// h never hits HBM: pooled sum/max accumulate in registers -> shfl -> LDS.
__global__ __launch_bounds__(256) void k_agg_pool(
    const ushort* __restrict__ zb, const float* __restrict__ el,
    const float* __restrict__ er, const int* __restrict__ off,
    const int* __restrict__ srcs, const float* __restrict__ bias,
    const float* __restrict__ r1W, const float* __restrict__ r1b,
    const float* __restrict__ r2W, const float* __restrict__ r2b,
    float* __restrict__ out) {
  __shared__ float sumb[4][HID4];
  __shared__ float maxb[4][HID4];
  __shared__ float pooled[3 * HID4];
  __shared__ float part[4][HID];
  __shared__ float mid[HID];
  int g = blockIdx.x;
  int t = threadIdx.x;
  int w = t >> 6;
  int lane = t & 63;
  int grp = lane >> 4;
  int li = lane & 15;
  int h = li >> 2;
  int c = li * 16;

  float bb[16];
#pragma unroll
  for (int j = 0; j < 16; j += 4) {
    float4 b4 = *(const float4*)(bias + c + j);
    bb[j] = b4.x; bb[j + 1] = b4.y; bb[j + 2] = b4.z; bb[j + 3] = b4.w;
  }

  float psum[16], pmax[16];
#pragma unroll
  for (int j = 0; j < 16; ++j) { psum[j] = 0.f; pmax[j] = -1e30f; }

  for (int it = 0; it < 4; ++it) {
    int slot = it * 16 + w * 4 + grp;
    if (slot < NODES_PER_G) {
      int n = g * NODES_PER_G + slot;
      int beg = off[n], end = off[n + 1];
      float erh = er[(size_t)n * NHEAD + h];
      float s = 0.f;
      float acc[16];
#pragma unroll
      for (int j = 0; j < 16; ++j) acc[j] = 0.f;

      float e0 = 0.f, e1 = 0.f, e2 = 0.f;
      int4 za0 = make_int4(0, 0, 0, 0), zb0 = za0;
      int4 za1 = za0, zb1 = za0, za2 = za0, zb2 = za0;
      if (beg < end) {
        int sn = srcs[beg];
        e0 = el[(size_t)sn * NHEAD + h];
        const ushort* zp = zb + (size_t)sn * HID4 + c;
        za0 = *(const int4*)zp; zb0 = *(const int4*)(zp + 8);
      }
      if (beg + 1 < end) {
        int sn = srcs[beg + 1];
        e1 = el[(size_t)sn * NHEAD + h];
        const ushort* zp = zb + (size_t)sn * HID4 + c;
        za1 = *(const int4*)zp; zb1 = *(const int4*)(zp + 8);
      }
      if (beg + 2 < end) {
        int sn = srcs[beg + 2];
        e2 = el[(size_t)sn * NHEAD + h];
        const ushort* zp = zb + (size_t)sn * HID4 + c;
        za2 = *(const int4*)zp; zb2 = *(const int4*)(zp + 8);
      }
      for (int p = beg; p < end; ++p) {
        float ev = e0;
        int4 va = za0, vb = zb0;
        e0 = e1; za0 = za1; zb0 = zb1;
        e1 = e2; za1 = za2; zb1 = zb2;
        if (p + 3 < end) {
          int sn = srcs[p + 3];
          e2 = el[(size_t)sn * NHEAD + h];
          const ushort* zp = zb + (size_t)sn * HID4 + c;
          za2 = *(const int4*)zp; zb2 = *(const int4*)(zp + 8);
        }
        float pv = __expf(leaky(ev + erh));
        s += pv;
        const ushort* ua = (const ushort*)&va;
        const ushort* ub = (const ushort*)&vb;
#pragma unroll
        for (int j = 0; j < 8; ++j) acc[j] = fmaf(pv, bf2f(ua[j]), acc[j]);
#pragma unroll
        for (int j = 0; j < 8; ++j) acc[8 + j] = fmaf(pv, bf2f(ub[j]), acc[8 + j]);
      }
      float inv = (s > 0.f) ? 1.f / s : 0.f;
#pragma unroll
      for (int j = 0; j < 16; ++j) {
        float v = bf2f(f2bf(fmaxf(acc[j] * inv + bb[j], 0.f)));  // match bf16 h
        psum[j] += v;
        pmax[j] = fmaxf(pmax[j], v);
      }
    }
  }

  // reduce across the 4 node-groups of this wave (lanes li, li+16, li+32, li+48)
#pragma unroll
  for (int j = 0; j < 16; ++j) {
    psum[j] += __shfl_xor(psum[j], 16, 64);
    psum[j] += __shfl_xor(psum[j], 32, 64);
    pmax[j] = fmaxf(pmax[j], __shfl_xor(pmax[j], 16, 64));
    pmax[j] = fmaxf(pmax[j], __shfl_xor(pmax[j], 32, 64));
  }
  if (lane < 16) {
#pragma unroll
    for (int j = 0; j < 16; ++j) {
      sumb[w][c + j] = psum[j];
      maxb[w][c + j] = pmax[j];
    }
  }
  __syncthreads();

  // combine waves -> pooled[mean|max|sum]
  {
    float ssum = sumb[0][t] + sumb[1][t] + sumb[2][t] + sumb[3][t];
    float smax = fmaxf(fmaxf(maxb[0][t], maxb[1][t]), fmaxf(maxb[2][t], maxb[3][t]));
    pooled[t] = ssum / (float)NODES_PER_G;
    pooled[HID4 + t] = smax;
    pooled[2 * HID4 + t] = ssum;
  }
  __syncthreads();

  // r1 MLP (768 -> 64, relu) then r2 (64 -> 128)
  {
    int o = t & 63, chunk = t >> 6;
    float acc = 0.f;
    int k0 = chunk * 192;
    for (int k = k0; k < k0 + 192; ++k) acc = fmaf(pooled[k], r1W[k * HID + o], acc);
    part[chunk][o] = acc;
  }
  __syncthreads();
  if (t < HID) {
    float acc = r1b[t] + part[0][t] + part[1][t] + part[2][t] + part[3][t];
    mid[t] = fmaxf(acc, 0.f);
  }
  __syncthreads();
  if (t < OUT_DIM) {
    float acc = r2b[t];
    for (int k = 0; k < HID; ++k) acc = fmaf(mid[k], r2W[k * OUT_DIM + t], acc);
    out[(size_t)g * OUT_DIM + t] = acc;
  }
}

// ---------------------------------------------------------------- launch
extern "C" void kernel_launch(void* const* d_in, const int* in_sizes, int n_in,
                              void* d_out, int out_size, void* d_ws, size_t ws_size,
                              hipStream_t stream) {
  const float* node_feat = (const float*)d_in[0];
  const int* src = (const int*)d_in[1];
  const int* dst = (const int*)d_in[2];
  const float* enc_W = (const float*)d_in[4];
  const float* enc_b = (const float*)d_in[5];
  const float* Wl[3] = {(const float*)d_in[6], (const float*)d_in[10], (const float*)d_in[14]};
  const float* all_[3] = {(const float*)d_in[7], (const float*)d_in[11], (const float*)d_in[15]};
  const float* arl[3] = {(const float*)d_in[8], (const float*)d_in[12], (const float*)d_in[16]};
  const float* bl[3] = {(const float*)d_in[9], (const float*)d_in[13], (const float*)d_in[17]};
  const float* r1W = (const float*)d_in[18];
  const float* r1b = (const float*)d_in[19];
  const float* r2W = (const float*)d_in[20];
  const float* r2b = (const float*)d_in[21];
  float* out = (float*)d_out;

  char* p = (char*)d_ws;
  auto alloc = [&](size_t bytes) {
    void* r = (void*)p;
    p += (bytes + 255) & ~(size_t)255;
    return r;
  };
  int* off = (int*)alloc((N_NODES + 1) * sizeof(int));
  int* cursor = (int*)alloc(N_NODES * sizeof(int));
  int* srcs = (int*)alloc(N_EDGES * sizeof(int));
  int* blksum = (int*)alloc(256 * sizeof(int));
  float* el = (float*)alloc((size_t)N_NODES * NHEAD * sizeof(float));
  float* er = (float*)alloc((size_t)N_NODES * NHEAD * sizeof(float));
  ushort* Qb = (ushort*)alloc((size_t)N_NODES * HID4 * sizeof(ushort));
  ushort* Pb = (ushort*)alloc((size_t)N_NODES * HID4 * sizeof(ushort));
  ushort* Wte = (ushort*)alloc((size_t)HID * ENC_KP * sizeof(ushort));
  ushort* Wt0 = (ushort*)alloc((size_t)HID4 * HID * sizeof(ushort));
  ushort* Wt1 = (ushort*)alloc((size_t)HID4 * HID4 * sizeof(ushort));
  ushort* Wt2 = (ushort*)alloc((size_t)HID4 * HID4 * sizeof(ushort));
  ushort* Wlr0 = (ushort*)alloc((size_t)16 * HID * sizeof(ushort));
  ushort* Wlr1 = (ushort*)alloc((size_t)16 * HID4 * sizeof(ushort));
  ushort* Wlr2 = (ushort*)alloc((size_t)16 * HID4 * sizeof(ushort));

  // ---- CSR build (deterministic via per-segment value sort)
  hipMemsetAsync(off, 0, (N_NODES + 1) * sizeof(int), stream);
  hipMemsetAsync(cursor, 0, N_NODES * sizeof(int), stream);
  k_count<<<(N_EDGES + 255) / 256, 256, 0, stream>>>(dst, off);
  const int SCAN_N = N_NODES + 1;
  const int NB = (SCAN_N + 1023) / 1024;
  k_scan1<<<NB, 256, 0, stream>>>(off, SCAN_N, blksum);
  k_scan2<<<1, 256, 0, stream>>>(blksum, NB);
  k_scan3<<<NB, 256, 0, stream>>>(off, SCAN_N, blksum);
  k_scatter<<<(N_EDGES + 255) / 256, 256, 0, stream>>>(dst, src, off, cursor, srcs);
  k_sortseg<<<(N_NODES + 255) / 256, 256, 0, stream>>>(off, srcs);

  // ---- all weight prep in one launch
  const int PREP_N = HID * ENC_KP + HID * HID4 + 2 * HID4 * HID4 +
                     16 * (HID + HID4 + HID4);
  k_prep<<<(PREP_N + 255) / 256, 256, 0, stream>>>(
      enc_W, Wl[0], Wl[1], Wl[2], all_[0], arl[0], all_[1], arl[1], all_[2], arl[2],
      Wte, Wt0, Wt1, Wt2, Wlr0, Wlr1, Wlr2);

  // ---- encoder MFMA GEMM (fp32 conversion fused into staging) -> Pb (bf16)
  k_enc_mfma<<<(N_NODES + 127) / 128, 256, 0, stream>>>(node_feat, Wte, enc_b, Pb);

  // ---- layers 0,1: GEMM (+el/er via MFMA) ; agg -> Pb
  const int NRP = (N_NODES + 127) / 128;
  const int GEMM_BLOCKS = ((NRP + 7) / 8) * 16;
  const int AGG_BLOCKS = ((N_NODES + 3) / 4 + 3) / 4;
  k_gemm_mfma<HID><<<GEMM_BLOCKS, 256, 0, stream>>>(Pb, Wt0, Wlr0, Qb, el, er, N_NODES);
  k_agg<<<AGG_BLOCKS, 256, 0, stream>>>(Qb, el, er, off, srcs, bl[0], Pb);
  k_gemm_mfma<HID4><<<GEMM_BLOCKS, 256, 0, stream>>>(Pb, Wt1, Wlr1, Qb, el, er, N_NODES);
  k_agg<<<AGG_BLOCKS, 256, 0, stream>>>(Qb, el, er, off, srcs, bl[1], Pb);

  // ---- layer 2: GEMM then fused agg+pool+MLP (h never hits HBM)
  k_gemm_mfma<HID4><<<GEMM_BLOCKS, 256, 0, stream>>>(Pb, Wt2, Wlr2, Qb, el, er, N_NODES);
  k_agg_pool<<<N_GRAPHS, 256, 0, stream>>>(Qb, el, er, off, srcs, bl[2],
                                           r1W, r1b, r2W, r2b, out);
}